// Round 1
// baseline (6600.132 us; speedup 1.0000x reference)
//
#include <hip/hip_runtime.h>
#include <cstdint>
#include <cstddef>

#define B_ 64
#define T_ 20
#define A_ 5
#define DG 768
#define DM 1024
#define VOC 50260
#define FEAT_ 32768

// ---------------------------------------------------------------------------
// Generic fp32 GEMM:  C[M,N] = A[M,K] @ W[N,K]^T (+ bias[n]) (+ ADDm[m,n])
// SPLIT: grid.z K-splits, atomicAdd epilogue (C must be pre-zeroed; bias added
//        by split 0 only).
// REMAP: rows are r = t*64+b (time-major); write C[(b*20+t)*N + n] instead.
// ---------------------------------------------------------------------------
template<int BM, int BN, int BK, int TM, int TN, bool ADD, bool SPLIT, bool REMAP>
__global__ __launch_bounds__(256)
void gemm_f32(const float* __restrict__ A, const float* __restrict__ W,
              const float* __restrict__ bias, const float* __restrict__ ADDm,
              float* __restrict__ C, int M, int N, int K, int k_len)
{
  static_assert((BM / TM) * (BN / TN) == 256, "need 256 threads");
  __shared__ float As[BK][BM + 4];
  __shared__ float Ws[BK][BN + 4];
  const int tid = (int)threadIdx.x;
  constexpr int NCG = BN / TN;
  const int tc = tid % NCG;
  const int tr = tid / NCG;
  const int m0 = (int)blockIdx.y * BM;
  const int n0 = (int)blockIdx.x * BN;
  const int ks = SPLIT ? (int)blockIdx.z * k_len : 0;

  float acc[TM][TN];
#pragma unroll
  for (int i = 0; i < TM; ++i)
#pragma unroll
    for (int j = 0; j < TN; ++j) acc[i][j] = 0.f;

  for (int k0 = ks; k0 < ks + k_len; k0 += BK) {
#pragma unroll
    for (int i = tid; i < BM * BK; i += 256) {
      int mm = i / BK, kk = i % BK;
      int gm = m0 + mm;
      As[kk][mm] = (gm < M) ? A[(size_t)gm * K + k0 + kk] : 0.f;
    }
#pragma unroll
    for (int i = tid; i < BN * BK; i += 256) {
      int nn = i / BK, kk = i % BK;
      int gn = n0 + nn;
      Ws[kk][nn] = (gn < N) ? W[(size_t)gn * K + k0 + kk] : 0.f;
    }
    __syncthreads();
#pragma unroll
    for (int kk = 0; kk < BK; ++kk) {
      float a[TM], bq[TN];
#pragma unroll
      for (int i = 0; i < TM; ++i) a[i] = As[kk][tr * TM + i];
#pragma unroll
      for (int j = 0; j < TN; ++j) bq[j] = Ws[kk][tc * TN + j];
#pragma unroll
      for (int i = 0; i < TM; ++i)
#pragma unroll
        for (int j = 0; j < TN; ++j)
          acc[i][j] = fmaf(a[i], bq[j], acc[i][j]);
    }
    __syncthreads();
  }

#pragma unroll
  for (int i = 0; i < TM; ++i) {
    const int gm = m0 + tr * TM + i;
    if (gm >= M) continue;
#pragma unroll
    for (int j = 0; j < TN; ++j) {
      const int gn = n0 + tc * TN + j;
      if (gn >= N) continue;
      float v = acc[i][j];
      if (SPLIT) {
        if (blockIdx.z == 0 && bias != nullptr) v += bias[gn];
        atomicAdd(&C[(size_t)gm * N + gn], v);
      } else {
        if (bias != nullptr) v += bias[gn];
        if (ADD) v += ADDm[(size_t)gm * N + gn];
        size_t ci = REMAP ? ((size_t)((gm & 63) * 20 + (gm >> 6)) * N + gn)
                          : ((size_t)gm * N + gn);
        C[ci] = v;
      }
    }
  }
}

// ---------------------------------------------------------------------------
__global__ void addvec(const float* __restrict__ a, const float* __restrict__ b,
                       float* __restrict__ o, int n)
{
  int i = blockIdx.x * blockDim.x + threadIdx.x;
  if (i < n) o[i] = a[i] + b[i];
}

// attr[b][a][:] = wte[attributes[b][a]];  sattr = sigmoid(attr)
__global__ __launch_bounds__(256)
void gather_attr(const int* __restrict__ attrs, const float* __restrict__ wte,
                 float* __restrict__ attr, float* __restrict__ sattr)
{
  const int ba = blockIdx.x;              // 0..319 = b*5+a
  const int idx = attrs[ba];
  const float* src = wte + (size_t)idx * DG;
  for (int e = threadIdx.x; e < DG; e += 256) {
    float v = src[e];
    attr[(size_t)ba * DG + e] = v;
    sattr[(size_t)ba * DG + e] = 1.f / (1.f + expf(-v));
  }
}

// input_emb row r=t*64+b: t==0 -> first_inputs[b], else wte[caption[b][t-1]]
__global__ __launch_bounds__(256)
void build_input_emb(const float* __restrict__ fi, const int* __restrict__ cap,
                     const float* __restrict__ wte, float* __restrict__ emb)
{
  const int r = blockIdx.x;               // 0..1279
  const int t = r >> 6, b = r & 63;
  const float* src = (t == 0) ? (fi + (size_t)b * DG)
                              : (wte + (size_t)cap[b * T_ + (t - 1)] * DG);
  for (int e = threadIdx.x; e < DG; e += 256)
    emb[(size_t)r * DG + e] = src[e];
}

// per (b,t) row: scores over 5 attrs -> softmax -> ctx
__global__ __launch_bounds__(256)
void attention_kernel(const float* __restrict__ q, const float* __restrict__ av,
                      float* __restrict__ ctx)
{
  const int r = blockIdx.x;
  const int b = r & 63;
  const int tid = (int)threadIdx.x;
  const float* qr = q + (size_t)r * DG;
  const float* ab = av + (size_t)b * A_ * DG;
  float p0 = 0, p1 = 0, p2 = 0, p3 = 0, p4 = 0;
  for (int e = tid; e < DG; e += 256) {
    float qv = qr[e];
    p0 += qv * ab[0 * DG + e];
    p1 += qv * ab[1 * DG + e];
    p2 += qv * ab[2 * DG + e];
    p3 += qv * ab[3 * DG + e];
    p4 += qv * ab[4 * DG + e];
  }
#pragma unroll
  for (int off = 32; off > 0; off >>= 1) {
    p0 += __shfl_down(p0, off, 64);
    p1 += __shfl_down(p1, off, 64);
    p2 += __shfl_down(p2, off, 64);
    p3 += __shfl_down(p3, off, 64);
    p4 += __shfl_down(p4, off, 64);
  }
  __shared__ float sred[4][5];
  __shared__ float wts[5];
  const int lane = tid & 63, wv = tid >> 6;
  if (lane == 0) {
    sred[wv][0] = p0; sred[wv][1] = p1; sred[wv][2] = p2;
    sred[wv][3] = p3; sred[wv][4] = p4;
  }
  __syncthreads();
  if (tid == 0) {
    float s[5];
#pragma unroll
    for (int a = 0; a < 5; ++a)
      s[a] = sred[0][a] + sred[1][a] + sred[2][a] + sred[3][a];
    float mx = s[0];
#pragma unroll
    for (int a = 1; a < 5; ++a) mx = fmaxf(mx, s[a]);
    float sum = 0.f;
#pragma unroll
    for (int a = 0; a < 5; ++a) { float e_ = expf(s[a] - mx); wts[a] = e_; sum += e_; }
    float inv = 1.f / sum;
#pragma unroll
    for (int a = 0; a < 5; ++a) wts[a] *= inv;
  }
  __syncthreads();
  const float w0 = wts[0], w1 = wts[1], w2 = wts[2], w3 = wts[3], w4 = wts[4];
  for (int e = tid; e < DG; e += 256) {
    float v = w0 * ab[0 * DG + e] + w1 * ab[1 * DG + e] + w2 * ab[2 * DG + e] +
              w3 * ab[3 * DG + e] + w4 * ab[4 * DG + e];
    ctx[(size_t)r * DG + e] = v;
  }
}

// gates[64,4096] (i,f,g,o) + c -> new c, h; also store h into hs slice
__global__ __launch_bounds__(256)
void lstm_pointwise(const float* __restrict__ g, float* __restrict__ c,
                    float* __restrict__ h, float* __restrict__ hs_t)
{
  const int i = blockIdx.x * 256 + threadIdx.x;   // 0..65535
  const int b = i >> 10, d = i & 1023;
  const float* gb = g + (size_t)b * (4 * DM);
  float ig = gb[d], fg = gb[DM + d], gg = gb[2 * DM + d], og = gb[3 * DM + d];
  float si = 1.f / (1.f + expf(-ig));
  float sf = 1.f / (1.f + expf(-fg));
  float so = 1.f / (1.f + expf(-og));
  float tg = tanhf(gg);
  float c2 = sf * c[i] + si * tg;
  float h2 = so * tanhf(c2);
  c[i] = c2;
  h[i] = h2;
  hs_t[i] = h2;
}

// ---------------------------------------------------------------------------
extern "C" void kernel_launch(void* const* d_in, const int* in_sizes, int n_in,
                              void* d_out, int out_size, void* d_ws, size_t ws_size,
                              hipStream_t stream)
{
  (void)in_sizes; (void)n_in; (void)out_size; (void)ws_size;

  const int*   caption    = (const int*)  d_in[0];
  const float* fm         = (const float*)d_in[1];
  const int*   attrs      = (const int*)  d_in[2];
  const float* wte        = (const float*)d_in[3];
  const float* fc_w       = (const float*)d_in[4];
  const float* fc_b       = (const float*)d_in[5];
  const float* hh_w       = (const float*)d_in[6];
  const float* hh_b       = (const float*)d_in[7];
  const float* cc_w       = (const float*)d_in[8];
  const float* cc_b       = (const float*)d_in[9];
  const float* lm_w       = (const float*)d_in[10];
  const float* lm_b       = (const float*)d_in[11];
  const float* iaw_w      = (const float*)d_in[12];
  const float* iaw_b      = (const float*)d_in[13];
  const float* iau_w      = (const float*)d_in[14];
  const float* iau_b      = (const float*)d_in[15];
  const float* indiag_w   = (const float*)d_in[16];
  const float* indiag_b   = (const float*)d_in[17];
  const float* indomain_w = (const float*)d_in[18];
  const float* indomain_b = (const float*)d_in[19];
  const float* oav_w      = (const float*)d_in[20];
  const float* oav_b      = (const float*)d_in[21];
  const float* outdiag_w  = (const float*)d_in[22];
  const float* outdiag_b  = (const float*)d_in[23];
  const float* outdomain_w= (const float*)d_in[24];
  const float* outdomain_b= (const float*)d_in[25];
  const float* w_ih       = (const float*)d_in[26];
  const float* b_ih       = (const float*)d_in[27];
  const float* w_hh       = (const float*)d_in[28];
  const float* b_hh       = (const float*)d_in[29];

  float* out = (float*)d_out;
  float* ws  = (float*)d_ws;

  // ---- workspace layout (floats). first_inputs/hidden/cell must stay first
  //      and contiguous (zeroed once for the atomic-split GEMMs).
  size_t o = 0;
  float* first_inputs = ws + o; o += (size_t)B_ * DG;       // 49152
  float* hidden       = ws + o; o += (size_t)B_ * DM;       // 65536
  float* cell         = ws + o; o += (size_t)B_ * DM;       // 65536
  float* mi_init      = ws + o; o += (size_t)B_ * DM;
  float* attr         = ws + o; o += (size_t)B_ * A_ * DG;
  float* sattr        = ws + o; o += (size_t)B_ * A_ * DG;
  float* iemb         = ws + o; o += (size_t)1280 * DG;
  float* m1           = ws + o; o += (size_t)1280 * DG;
  float* ctx          = ws + o; o += (size_t)1280 * DG;
  float* t768         = ws + o; o += (size_t)1280 * DG;
  float* minp         = ws + o; o += (size_t)1280 * DM;
  float* XG           = ws + o; o += (size_t)1280 * 4 * DM; // 5.24M floats
  float* hs           = ws + o; o += (size_t)1280 * DM;
  float* gates        = ws + o; o += (size_t)B_ * 4 * DM;
  float* bias2        = ws + o; o += (size_t)4 * DM;
  // buffer reuse (lifetimes verified):
  float* m1o   = m1;    // m1 dead after input attention
  float* ctxo  = ctx;   // ctx dead after t768 GEMM
  float* t1024 = minp;  // model_inputs dead after XG GEMM
  float* outb  = XG;    // XG dead after LSTM loop

  const dim3 blk(256);

  // zero atomic-GEMM outputs (first_inputs|hidden|cell contiguous)
  hipMemsetAsync(d_ws, 0, (size_t)(B_ * DG + 2 * B_ * DM) * sizeof(float), stream);

  // bias2 = b_ih + b_hh
  addvec<<<dim3(16), blk, 0, stream>>>(b_ih, b_hh, bias2, 4 * DM);

  // fm GEMMs (K=32768, 16-way K-split, atomic)
  gemm_f32<64,32,16,4,2,false,true,false><<<dim3(DG / 32, 1, 16), blk, 0, stream>>>(
      fm, fc_w, fc_b, nullptr, first_inputs, B_, DG, FEAT_, FEAT_ / 16);
  gemm_f32<64,32,16,4,2,false,true,false><<<dim3(DM / 32, 1, 16), blk, 0, stream>>>(
      fm, hh_w, hh_b, nullptr, hidden, B_, DM, FEAT_, FEAT_ / 16);
  gemm_f32<64,32,16,4,2,false,true,false><<<dim3(DM / 32, 1, 16), blk, 0, stream>>>(
      fm, cc_w, cc_b, nullptr, cell, B_, DM, FEAT_, FEAT_ / 16);

  gather_attr<<<dim3(B_ * A_), blk, 0, stream>>>(attrs, wte, attr, sattr);
  build_input_emb<<<dim3(1280), blk, 0, stream>>>(first_inputs, caption, wte, iemb);

  // mi_init = first_inputs @ iaw^T + iaw_b
  gemm_f32<64,16,16,4,1,false,false,false><<<dim3(DM / 16, 1), blk, 0, stream>>>(
      first_inputs, iaw_w, iaw_b, nullptr, mi_init, B_, DM, DG, DG);

  // m1 = iemb @ iau^T + iau_b
  gemm_f32<64,64,16,4,4,false,false,false><<<dim3(DG / 64, 20), blk, 0, stream>>>(
      iemb, iau_w, iau_b, nullptr, m1, 1280, DG, DG, DG);
  attention_kernel<<<dim3(1280), blk, 0, stream>>>(m1, attr, ctx);
  // t768 = ctx @ indiag^T + indiag_b + iemb
  gemm_f32<64,64,16,4,4,true,false,false><<<dim3(DG / 64, 20), blk, 0, stream>>>(
      ctx, indiag_w, indiag_b, iemb, t768, 1280, DG, DG, DG);
  // model_inputs = t768 @ indomain^T + indomain_b
  gemm_f32<64,64,16,4,4,false,false,false><<<dim3(DM / 64, 20), blk, 0, stream>>>(
      t768, indomain_w, indomain_b, nullptr, minp, 1280, DM, DG, DG);

  // XG rows 0..63 from mi_init; rows 64..1279 from model_inputs[:,1:]
  gemm_f32<64,16,16,4,1,false,false,false><<<dim3(4 * DM / 16, 1), blk, 0, stream>>>(
      mi_init, w_ih, bias2, nullptr, XG, B_, 4 * DM, DM, DM);
  gemm_f32<128,128,16,8,8,false,false,false><<<dim3(4 * DM / 128, 10), blk, 0, stream>>>(
      minp + (size_t)64 * DM, w_ih, bias2, nullptr, XG + (size_t)64 * 4 * DM,
      1216, 4 * DM, DM, DM);

  // LSTM: 20 sequential steps; h=hidden, c=cell updated in place
  for (int t = 0; t < T_; ++t) {
    gemm_f32<64,16,16,4,1,true,false,false><<<dim3(4 * DM / 16, 1), blk, 0, stream>>>(
        hidden, w_hh, nullptr, XG + (size_t)t * B_ * 4 * DM, gates, B_, 4 * DM, DM, DM);
    lstm_pointwise<<<dim3((B_ * DM) / 256), blk, 0, stream>>>(
        gates, cell, hidden, hs + (size_t)t * B_ * DM);
  }

  // output attention
  gemm_f32<64,64,16,4,4,false,false,false><<<dim3(DG / 64, 20), blk, 0, stream>>>(
      hs, oav_w, oav_b, nullptr, m1o, 1280, DG, DM, DM);
  attention_kernel<<<dim3(1280), blk, 0, stream>>>(m1o, sattr, ctxo);
  // t1024 = ctxo @ outdiag^T + outdiag_b + hs
  gemm_f32<64,64,16,4,4,true,false,false><<<dim3(DM / 64, 20), blk, 0, stream>>>(
      ctxo, outdiag_w, outdiag_b, hs, t1024, 1280, DM, DG, DG);
  // out = t1024 @ outdomain^T + outdomain_b
  gemm_f32<64,64,16,4,4,false,false,false><<<dim3(DM / 64, 20), blk, 0, stream>>>(
      t1024, outdomain_w, outdomain_b, nullptr, outb, 1280, DM, DM, DM);

  // logits = out @ lm_w^T + lm_b, written [b][t][vocab]
  gemm_f32<128,128,16,8,8,false,false,true><<<dim3((VOC + 127) / 128, 10), blk, 0, stream>>>(
      outb, lm_w, lm_b, nullptr, out, 1280, VOC, DM, DM);
}

// Round 2
// 4237.820 us; speedup vs baseline: 1.5574x; 1.5574x over previous
//
#include <hip/hip_runtime.h>
#include <cstdint>
#include <cstddef>

#define B_ 64
#define T_ 20
#define A_ 5
#define DG 768
#define DM 1024
#define VOC 50260
#define FEAT_ 32768

typedef __attribute__((ext_vector_type(8))) short short8;
typedef __attribute__((ext_vector_type(4))) float f32x4;
typedef __attribute__((ext_vector_type(4))) unsigned int u32x4;

__device__ __forceinline__ unsigned short f2bf(float x) {
  unsigned u = __builtin_bit_cast(unsigned, x);
  unsigned r = u + 0x7FFFu + ((u >> 16) & 1u);
  return (unsigned short)(r >> 16);
}

// ---------------------------------------------------------------------------
// Generic fp32 GEMM:  C[M,N] = A[M,K] @ W[N,K]^T (+ bias[n]) (+ ADDm[m,n])
// SPLIT: grid.z K-splits, atomicAdd epilogue (C must be pre-zeroed; bias added
//        by split 0 only).
// ---------------------------------------------------------------------------
template<int BM, int BN, int BK, int TM, int TN, bool ADD, bool SPLIT>
__global__ __launch_bounds__(256)
void gemm_f32(const float* __restrict__ A, const float* __restrict__ W,
              const float* __restrict__ bias, const float* __restrict__ ADDm,
              float* __restrict__ C, int M, int N, int K, int k_len)
{
  static_assert((BM / TM) * (BN / TN) == 256, "need 256 threads");
  __shared__ float As[BK][BM + 4];
  __shared__ float Ws[BK][BN + 4];
  const int tid = (int)threadIdx.x;
  constexpr int NCG = BN / TN;
  const int tc = tid % NCG;
  const int tr = tid / NCG;
  const int m0 = (int)blockIdx.y * BM;
  const int n0 = (int)blockIdx.x * BN;
  const int ks = SPLIT ? (int)blockIdx.z * k_len : 0;

  float acc[TM][TN];
#pragma unroll
  for (int i = 0; i < TM; ++i)
#pragma unroll
    for (int j = 0; j < TN; ++j) acc[i][j] = 0.f;

  for (int k0 = ks; k0 < ks + k_len; k0 += BK) {
#pragma unroll
    for (int i = tid; i < BM * BK; i += 256) {
      int mm = i / BK, kk = i % BK;
      int gm = m0 + mm;
      As[kk][mm] = (gm < M) ? A[(size_t)gm * K + k0 + kk] : 0.f;
    }
#pragma unroll
    for (int i = tid; i < BN * BK; i += 256) {
      int nn = i / BK, kk = i % BK;
      int gn = n0 + nn;
      Ws[kk][nn] = (gn < N) ? W[(size_t)gn * K + k0 + kk] : 0.f;
    }
    __syncthreads();
#pragma unroll
    for (int kk = 0; kk < BK; ++kk) {
      float a[TM], bq[TN];
#pragma unroll
      for (int i = 0; i < TM; ++i) a[i] = As[kk][tr * TM + i];
#pragma unroll
      for (int j = 0; j < TN; ++j) bq[j] = Ws[kk][tc * TN + j];
#pragma unroll
      for (int i = 0; i < TM; ++i)
#pragma unroll
        for (int j = 0; j < TN; ++j)
          acc[i][j] = fmaf(a[i], bq[j], acc[i][j]);
    }
    __syncthreads();
  }

#pragma unroll
  for (int i = 0; i < TM; ++i) {
    const int gm = m0 + tr * TM + i;
    if (gm >= M) continue;
#pragma unroll
    for (int j = 0; j < TN; ++j) {
      const int gn = n0 + tc * TN + j;
      if (gn >= N) continue;
      float v = acc[i][j];
      if (SPLIT) {
        if (blockIdx.z == 0 && bias != nullptr) v += bias[gn];
        atomicAdd(&C[(size_t)gm * N + gn], v);
      } else {
        if (bias != nullptr) v += bias[gn];
        if (ADD) v += ADDm[(size_t)gm * N + gn];
        C[(size_t)gm * N + gn] = v;
      }
    }
  }
}

// ---------------------------------------------------------------------------
// bf16-MFMA lm-head GEMM: out[remap(m)][n] = Abf[m] . W[n] + bias[n]
// Abf: [1280][1024] bf16 (pre-converted). W: [50260][1024] fp32, converted
// in-kernel during staging. 128x128 tile, BK=64, 4 waves (2x2), each 64x64.
// LDS layout: [row][64 k] bf16, 16B-chunk XOR swizzle: slot = c ^ (row&7).
// ---------------------------------------------------------------------------
__global__ __launch_bounds__(256)
void lm_gemm_bf16(const unsigned short* __restrict__ Abf,
                  const float* __restrict__ W,
                  const float* __restrict__ bias,
                  float* __restrict__ Cout)
{
  __shared__ unsigned short As[128 * 64];   // 16 KB
  __shared__ unsigned short Bs[128 * 64];   // 16 KB
  const int tid = (int)threadIdx.x;
  const int lane = tid & 63;
  const int w = tid >> 6;                   // wave 0..3
  const int wr = w >> 1, wc = w & 1;        // 2x2 wave grid, 64x64 each
  const int lhi = lane >> 4;                // 0..3
  const int llo = lane & 15;
  const int m0 = (int)blockIdx.x * 128;     // grid.x = 10 (M tiles)
  const int n0 = (int)blockIdx.y * 128;     // grid.y = 393 (N tiles)

  // staging coords: each thread owns row = tid>>1, chunks cbase..cbase+3
  const int srow = tid >> 1;                // 0..127
  const int cbase = (tid & 1) * 4;          // 0 or 4
  const int sxor = srow & 7;

  f32x4 acc[4][4] = {};

  const int gnrow = n0 + srow;
  const bool bvalid = gnrow < VOC;
  const unsigned short* agp = Abf + (size_t)(m0 + srow) * DM + cbase * 8;
  const float* bgp = W + (size_t)(bvalid ? gnrow : 0) * DM + cbase * 8;

  for (int step = 0; step < 16; ++step) {
    const int k0 = step * 64;
    __syncthreads();   // previous tile's reads complete

    // ---- stage A (bf16, reg-staged, swizzled write)
#pragma unroll
    for (int c = 0; c < 4; ++c) {
      short8 av = *(const short8*)(agp + k0 + c * 8);
      int slot = (cbase + c) ^ sxor;
      *(short8*)(&As[srow * 64 + slot * 8]) = av;
    }
    // ---- stage B (fp32 -> bf16 convert, swizzled write)
#pragma unroll
    for (int c = 0; c < 4; ++c) {
      float4 x0, x1;
      if (bvalid) {
        x0 = *(const float4*)(bgp + k0 + c * 8);
        x1 = *(const float4*)(bgp + k0 + c * 8 + 4);
      } else {
        x0 = make_float4(0.f, 0.f, 0.f, 0.f);
        x1 = make_float4(0.f, 0.f, 0.f, 0.f);
      }
      u32x4 pk;
      pk.x = (unsigned)f2bf(x0.x) | ((unsigned)f2bf(x0.y) << 16);
      pk.y = (unsigned)f2bf(x0.z) | ((unsigned)f2bf(x0.w) << 16);
      pk.z = (unsigned)f2bf(x1.x) | ((unsigned)f2bf(x1.y) << 16);
      pk.w = (unsigned)f2bf(x1.z) | ((unsigned)f2bf(x1.w) << 16);
      int slot = (cbase + c) ^ sxor;
      *(u32x4*)(&Bs[srow * 64 + slot * 8]) = pk;
    }
    __syncthreads();   // staging visible

    // ---- compute: 2 k-substeps of 32
#pragma unroll
    for (int ksu = 0; ksu < 2; ++ksu) {
      short8 af[4], bfr[4];
#pragma unroll
      for (int fm = 0; fm < 4; ++fm) {
        int row = wr * 64 + fm * 16 + llo;
        int slot = (ksu * 4 + lhi) ^ (row & 7);
        af[fm] = *(const short8*)(&As[row * 64 + slot * 8]);
      }
#pragma unroll
      for (int fn = 0; fn < 4; ++fn) {
        int row = wc * 64 + fn * 16 + llo;
        int slot = (ksu * 4 + lhi) ^ (row & 7);
        bfr[fn] = *(const short8*)(&Bs[row * 64 + slot * 8]);
      }
#pragma unroll
      for (int fm = 0; fm < 4; ++fm)
#pragma unroll
        for (int fn = 0; fn < 4; ++fn)
          acc[fm][fn] = __builtin_amdgcn_mfma_f32_16x16x32_bf16(
              af[fm], bfr[fn], acc[fm][fn], 0, 0, 0);
    }
  }

  // ---- epilogue: bias + time-major -> [b][t] remap
#pragma unroll
  for (int fn = 0; fn < 4; ++fn) {
    const int gn = n0 + wc * 64 + fn * 16 + llo;
    if (gn >= VOC) continue;
    const float bv = bias[gn];
#pragma unroll
    for (int fm = 0; fm < 4; ++fm) {
#pragma unroll
      for (int j = 0; j < 4; ++j) {
        const int gm = m0 + wr * 64 + fm * 16 + lhi * 4 + j;
        const int orow = (gm & 63) * T_ + (gm >> 6);
        Cout[(size_t)orow * VOC + gn] = acc[fm][fn][j] + bv;
      }
    }
  }
}

// f32 -> bf16 (RNE), 4 elems/thread
__global__ __launch_bounds__(256)
void cvt_f32_bf16(const float* __restrict__ in, unsigned short* __restrict__ op, int n4)
{
  int i = blockIdx.x * 256 + threadIdx.x;
  if (i >= n4) return;
  float4 v = ((const float4*)in)[i];
  unsigned p0 = (unsigned)f2bf(v.x) | ((unsigned)f2bf(v.y) << 16);
  unsigned p1 = (unsigned)f2bf(v.z) | ((unsigned)f2bf(v.w) << 16);
  ((uint2*)op)[i] = make_uint2(p0, p1);
}

// ---------------------------------------------------------------------------
__global__ void addvec(const float* __restrict__ a, const float* __restrict__ b,
                       float* __restrict__ o, int n)
{
  int i = blockIdx.x * blockDim.x + threadIdx.x;
  if (i < n) o[i] = a[i] + b[i];
}

__global__ __launch_bounds__(256)
void gather_attr(const int* __restrict__ attrs, const float* __restrict__ wte,
                 float* __restrict__ attr, float* __restrict__ sattr)
{
  const int ba = blockIdx.x;
  const int idx = attrs[ba];
  const float* src = wte + (size_t)idx * DG;
  for (int e = threadIdx.x; e < DG; e += 256) {
    float v = src[e];
    attr[(size_t)ba * DG + e] = v;
    sattr[(size_t)ba * DG + e] = 1.f / (1.f + expf(-v));
  }
}

__global__ __launch_bounds__(256)
void build_input_emb(const float* __restrict__ fi, const int* __restrict__ cap,
                     const float* __restrict__ wte, float* __restrict__ emb)
{
  const int r = blockIdx.x;
  const int t = r >> 6, b = r & 63;
  const float* src = (t == 0) ? (fi + (size_t)b * DG)
                              : (wte + (size_t)cap[b * T_ + (t - 1)] * DG);
  for (int e = threadIdx.x; e < DG; e += 256)
    emb[(size_t)r * DG + e] = src[e];
}

__global__ __launch_bounds__(256)
void attention_kernel(const float* __restrict__ q, const float* __restrict__ av,
                      float* __restrict__ ctx)
{
  const int r = blockIdx.x;
  const int b = r & 63;
  const int tid = (int)threadIdx.x;
  const float* qr = q + (size_t)r * DG;
  const float* ab = av + (size_t)b * A_ * DG;
  float p0 = 0, p1 = 0, p2 = 0, p3 = 0, p4 = 0;
  for (int e = tid; e < DG; e += 256) {
    float qv = qr[e];
    p0 += qv * ab[0 * DG + e];
    p1 += qv * ab[1 * DG + e];
    p2 += qv * ab[2 * DG + e];
    p3 += qv * ab[3 * DG + e];
    p4 += qv * ab[4 * DG + e];
  }
#pragma unroll
  for (int off = 32; off > 0; off >>= 1) {
    p0 += __shfl_down(p0, off, 64);
    p1 += __shfl_down(p1, off, 64);
    p2 += __shfl_down(p2, off, 64);
    p3 += __shfl_down(p3, off, 64);
    p4 += __shfl_down(p4, off, 64);
  }
  __shared__ float sred[4][5];
  __shared__ float wts[5];
  const int lane = tid & 63, wv = tid >> 6;
  if (lane == 0) {
    sred[wv][0] = p0; sred[wv][1] = p1; sred[wv][2] = p2;
    sred[wv][3] = p3; sred[wv][4] = p4;
  }
  __syncthreads();
  if (tid == 0) {
    float s[5];
#pragma unroll
    for (int a = 0; a < 5; ++a)
      s[a] = sred[0][a] + sred[1][a] + sred[2][a] + sred[3][a];
    float mx = s[0];
#pragma unroll
    for (int a = 1; a < 5; ++a) mx = fmaxf(mx, s[a]);
    float sum = 0.f;
#pragma unroll
    for (int a = 0; a < 5; ++a) { float e_ = expf(s[a] - mx); wts[a] = e_; sum += e_; }
    float inv = 1.f / sum;
#pragma unroll
    for (int a = 0; a < 5; ++a) wts[a] *= inv;
  }
  __syncthreads();
  const float w0 = wts[0], w1 = wts[1], w2 = wts[2], w3 = wts[3], w4 = wts[4];
  for (int e = tid; e < DG; e += 256) {
    float v = w0 * ab[0 * DG + e] + w1 * ab[1 * DG + e] + w2 * ab[2 * DG + e] +
              w3 * ab[3 * DG + e] + w4 * ab[4 * DG + e];
    ctx[(size_t)r * DG + e] = v;
  }
}

__global__ __launch_bounds__(256)
void lstm_pointwise(const float* __restrict__ g, float* __restrict__ c,
                    float* __restrict__ h, float* __restrict__ hs_t)
{
  const int i = blockIdx.x * 256 + threadIdx.x;
  const int b = i >> 10, d = i & 1023;
  const float* gb = g + (size_t)b * (4 * DM);
  float ig = gb[d], fg = gb[DM + d], gg = gb[2 * DM + d], og = gb[3 * DM + d];
  float si = 1.f / (1.f + expf(-ig));
  float sf = 1.f / (1.f + expf(-fg));
  float so = 1.f / (1.f + expf(-og));
  float tg = tanhf(gg);
  float c2 = sf * c[i] + si * tg;
  float h2 = so * tanhf(c2);
  c[i] = c2;
  h[i] = h2;
  hs_t[i] = h2;
}

// ---------------------------------------------------------------------------
extern "C" void kernel_launch(void* const* d_in, const int* in_sizes, int n_in,
                              void* d_out, int out_size, void* d_ws, size_t ws_size,
                              hipStream_t stream)
{
  (void)in_sizes; (void)n_in; (void)out_size; (void)ws_size;

  const int*   caption    = (const int*)  d_in[0];
  const float* fm         = (const float*)d_in[1];
  const int*   attrs      = (const int*)  d_in[2];
  const float* wte        = (const float*)d_in[3];
  const float* fc_w       = (const float*)d_in[4];
  const float* fc_b       = (const float*)d_in[5];
  const float* hh_w       = (const float*)d_in[6];
  const float* hh_b       = (const float*)d_in[7];
  const float* cc_w       = (const float*)d_in[8];
  const float* cc_b       = (const float*)d_in[9];
  const float* lm_w       = (const float*)d_in[10];
  const float* lm_b       = (const float*)d_in[11];
  const float* iaw_w      = (const float*)d_in[12];
  const float* iaw_b      = (const float*)d_in[13];
  const float* iau_w      = (const float*)d_in[14];
  const float* iau_b      = (const float*)d_in[15];
  const float* indiag_w   = (const float*)d_in[16];
  const float* indiag_b   = (const float*)d_in[17];
  const float* indomain_w = (const float*)d_in[18];
  const float* indomain_b = (const float*)d_in[19];
  const float* oav_w      = (const float*)d_in[20];
  const float* oav_b      = (const float*)d_in[21];
  const float* outdiag_w  = (const float*)d_in[22];
  const float* outdiag_b  = (const float*)d_in[23];
  const float* outdomain_w= (const float*)d_in[24];
  const float* outdomain_b= (const float*)d_in[25];
  const float* w_ih       = (const float*)d_in[26];
  const float* b_ih       = (const float*)d_in[27];
  const float* w_hh       = (const float*)d_in[28];
  const float* b_hh       = (const float*)d_in[29];

  float* out = (float*)d_out;
  float* ws  = (float*)d_ws;

  size_t o = 0;
  float* first_inputs = ws + o; o += (size_t)B_ * DG;
  float* hidden       = ws + o; o += (size_t)B_ * DM;
  float* cell         = ws + o; o += (size_t)B_ * DM;
  float* mi_init      = ws + o; o += (size_t)B_ * DM;
  float* attr         = ws + o; o += (size_t)B_ * A_ * DG;
  float* sattr        = ws + o; o += (size_t)B_ * A_ * DG;
  float* iemb         = ws + o; o += (size_t)1280 * DG;
  float* m1           = ws + o; o += (size_t)1280 * DG;
  float* ctx          = ws + o; o += (size_t)1280 * DG;
  float* t768         = ws + o; o += (size_t)1280 * DG;
  float* minp         = ws + o; o += (size_t)1280 * DM;
  float* XG           = ws + o; o += (size_t)1280 * 4 * DM;
  float* hs           = ws + o; o += (size_t)1280 * DM;
  float* gates        = ws + o; o += (size_t)B_ * 4 * DM;
  float* bias2        = ws + o; o += (size_t)4 * DM;
  // buffer reuse (lifetimes verified):
  float* m1o   = m1;    // m1 dead after input attention
  float* ctxo  = ctx;   // ctx dead after t768 GEMM
  float* t1024 = minp;  // model_inputs dead after XG GEMM
  float* outb  = XG;    // XG dead after LSTM loop
  unsigned short* Abf = (unsigned short*)t768;  // t768 dead after minp GEMM

  const dim3 blk(256);

  hipMemsetAsync(d_ws, 0, (size_t)(B_ * DG + 2 * B_ * DM) * sizeof(float), stream);

  addvec<<<dim3(16), blk, 0, stream>>>(b_ih, b_hh, bias2, 4 * DM);

  gemm_f32<64,32,16,4,2,false,true><<<dim3(DG / 32, 1, 16), blk, 0, stream>>>(
      fm, fc_w, fc_b, nullptr, first_inputs, B_, DG, FEAT_, FEAT_ / 16);
  gemm_f32<64,32,16,4,2,false,true><<<dim3(DM / 32, 1, 16), blk, 0, stream>>>(
      fm, hh_w, hh_b, nullptr, hidden, B_, DM, FEAT_, FEAT_ / 16);
  gemm_f32<64,32,16,4,2,false,true><<<dim3(DM / 32, 1, 16), blk, 0, stream>>>(
      fm, cc_w, cc_b, nullptr, cell, B_, DM, FEAT_, FEAT_ / 16);

  gather_attr<<<dim3(B_ * A_), blk, 0, stream>>>(attrs, wte, attr, sattr);
  build_input_emb<<<dim3(1280), blk, 0, stream>>>(first_inputs, caption, wte, iemb);

  gemm_f32<64,16,16,4,1,false,false><<<dim3(DM / 16, 1), blk, 0, stream>>>(
      first_inputs, iaw_w, iaw_b, nullptr, mi_init, B_, DM, DG, DG);

  gemm_f32<64,64,16,4,4,false,false><<<dim3(DG / 64, 20), blk, 0, stream>>>(
      iemb, iau_w, iau_b, nullptr, m1, 1280, DG, DG, DG);
  attention_kernel<<<dim3(1280), blk, 0, stream>>>(m1, attr, ctx);
  gemm_f32<64,64,16,4,4,true,false><<<dim3(DG / 64, 20), blk, 0, stream>>>(
      ctx, indiag_w, indiag_b, iemb, t768, 1280, DG, DG, DG);
  gemm_f32<64,64,16,4,4,false,false><<<dim3(DM / 64, 20), blk, 0, stream>>>(
      t768, indomain_w, indomain_b, nullptr, minp, 1280, DM, DG, DG);

  gemm_f32<64,16,16,4,1,false,false><<<dim3(4 * DM / 16, 1), blk, 0, stream>>>(
      mi_init, w_ih, bias2, nullptr, XG, B_, 4 * DM, DM, DM);
  gemm_f32<128,128,16,8,8,false,false><<<dim3(4 * DM / 128, 10), blk, 0, stream>>>(
      minp + (size_t)64 * DM, w_ih, bias2, nullptr, XG + (size_t)64 * 4 * DM,
      1216, 4 * DM, DM, DM);

  for (int t = 0; t < T_; ++t) {
    gemm_f32<64,16,16,4,1,true,false><<<dim3(4 * DM / 16, 1), blk, 0, stream>>>(
        hidden, w_hh, nullptr, XG + (size_t)t * B_ * 4 * DM, gates, B_, 4 * DM, DM, DM);
    lstm_pointwise<<<dim3((B_ * DM) / 256), blk, 0, stream>>>(
        gates, cell, hidden, hs + (size_t)t * B_ * DM);
  }

  gemm_f32<64,64,16,4,4,false,false><<<dim3(DG / 64, 20), blk, 0, stream>>>(
      hs, oav_w, oav_b, nullptr, m1o, 1280, DG, DM, DM);
  attention_kernel<<<dim3(1280), blk, 0, stream>>>(m1o, sattr, ctxo);
  gemm_f32<64,64,16,4,4,true,false><<<dim3(DM / 64, 20), blk, 0, stream>>>(
      ctxo, outdiag_w, outdiag_b, hs, t1024, 1280, DM, DG, DG);
  gemm_f32<64,64,16,4,4,false,false><<<dim3(DM / 64, 20), blk, 0, stream>>>(
      t1024, outdomain_w, outdomain_b, nullptr, outb, 1280, DM, DM, DM);

  // lm head: pre-convert A to bf16 (into dead t768), then bf16-MFMA GEMM
  cvt_f32_bf16<<<dim3((1280 * DM / 4 + 255) / 256), blk, 0, stream>>>(
      outb, Abf, 1280 * DM / 4);
  lm_gemm_bf16<<<dim3(10, (VOC + 127) / 128), blk, 0, stream>>>(
      Abf, lm_w, lm_b, out);
}

// Round 3
// 2204.055 us; speedup vs baseline: 2.9945x; 1.9227x over previous
//
#include <hip/hip_runtime.h>
#include <cstdint>
#include <cstddef>

#define B_ 64
#define T_ 20
#define A_ 5
#define DG 768
#define DM 1024
#define VOC 50260
#define FEAT_ 32768

typedef __attribute__((ext_vector_type(8))) short short8;
typedef __attribute__((ext_vector_type(4))) float f32x4;
typedef __attribute__((ext_vector_type(4))) unsigned int u32x4;

__device__ __forceinline__ unsigned short f2bf(float x) {
  unsigned u = __builtin_bit_cast(unsigned, x);
  unsigned r = u + 0x7FFFu + ((u >> 16) & 1u);
  return (unsigned short)(r >> 16);
}

// ---------------------------------------------------------------------------
// Generic fp32 GEMM (kept for mid-size layers):
// C[M,N] = A[M,K] @ W[N,K]^T (+ bias[n]) (+ ADDm[m,n])
// ---------------------------------------------------------------------------
template<int BM, int BN, int BK, int TM, int TN, bool ADD>
__global__ __launch_bounds__(256)
void gemm_f32(const float* __restrict__ A, const float* __restrict__ W,
              const float* __restrict__ bias, const float* __restrict__ ADDm,
              float* __restrict__ C, int M, int N, int K)
{
  static_assert((BM / TM) * (BN / TN) == 256, "need 256 threads");
  __shared__ float As[BK][BM + 4];
  __shared__ float Ws[BK][BN + 4];
  const int tid = (int)threadIdx.x;
  constexpr int NCG = BN / TN;
  const int tc = tid % NCG;
  const int tr = tid / NCG;
  const int m0 = (int)blockIdx.y * BM;
  const int n0 = (int)blockIdx.x * BN;

  float acc[TM][TN];
#pragma unroll
  for (int i = 0; i < TM; ++i)
#pragma unroll
    for (int j = 0; j < TN; ++j) acc[i][j] = 0.f;

  for (int k0 = 0; k0 < K; k0 += BK) {
#pragma unroll
    for (int i = tid; i < BM * BK; i += 256) {
      int mm = i / BK, kk = i % BK;
      int gm = m0 + mm;
      As[kk][mm] = (gm < M) ? A[(size_t)gm * K + k0 + kk] : 0.f;
    }
#pragma unroll
    for (int i = tid; i < BN * BK; i += 256) {
      int nn = i / BK, kk = i % BK;
      int gn = n0 + nn;
      Ws[kk][nn] = (gn < N) ? W[(size_t)gn * K + k0 + kk] : 0.f;
    }
    __syncthreads();
#pragma unroll
    for (int kk = 0; kk < BK; ++kk) {
      float a[TM], bq[TN];
#pragma unroll
      for (int i = 0; i < TM; ++i) a[i] = As[kk][tr * TM + i];
#pragma unroll
      for (int j = 0; j < TN; ++j) bq[j] = Ws[kk][tc * TN + j];
#pragma unroll
      for (int i = 0; i < TM; ++i)
#pragma unroll
        for (int j = 0; j < TN; ++j)
          acc[i][j] = fmaf(a[i], bq[j], acc[i][j]);
    }
    __syncthreads();
  }

#pragma unroll
  for (int i = 0; i < TM; ++i) {
    const int gm = m0 + tr * TM + i;
    if (gm >= M) continue;
#pragma unroll
    for (int j = 0; j < TN; ++j) {
      const int gn = n0 + tc * TN + j;
      if (gn >= N) continue;
      float v = acc[i][j];
      if (bias != nullptr) v += bias[gn];
      if (ADD) v += ADDm[(size_t)gm * N + gn];
      C[(size_t)gm * N + gn] = v;
    }
  }
}

// ---------------------------------------------------------------------------
// bf16 MFMA GEMM (128x128 tile, BK=64, 4 waves 2x2 of 64x64):
//   C[m][n] (or remapped) = Abf[m] . W[n] + bias[n]
// A pre-converted bf16; W fp32 converted inline during reg-staging.
// 1D grid, XCD-chunked n-major pair mapping: pair = (wg&7)*chunk + (wg>>3),
// nt = pair / MT, mt = pair % MT  -> blocks sharing a W N-panel land on the
// same XCD's L2. 2-phase pipeline: prefetch next K-step into regs during MFMA.
// ---------------------------------------------------------------------------
template<bool REMAP>
__global__ __launch_bounds__(256)
void mfma_gemm_bf16(const unsigned short* __restrict__ Abf,
                    const float* __restrict__ W,
                    const float* __restrict__ bias,
                    float* __restrict__ C,
                    int M, int N, int K, int MT, int chunk, int npairs)
{
  __shared__ unsigned short As[128 * 64];   // 16 KB
  __shared__ unsigned short Bs[128 * 64];   // 16 KB
  const int wg = (int)blockIdx.x;
  const int pair = (wg & 7) * chunk + (wg >> 3);
  if (pair >= npairs) return;
  const int nt = pair / MT, mt = pair % MT;
  const int m0 = mt * 128, n0 = nt * 128;

  const int tid = (int)threadIdx.x;
  const int lane = tid & 63;
  const int w = tid >> 6;
  const int wr = w >> 1, wc = w & 1;
  const int lhi = lane >> 4, llo = lane & 15;
  const int srow = tid >> 1;
  const int cbase = (tid & 1) * 4;
  const int sxor = srow & 7;
  const int NS = K >> 6;

  int arow = m0 + srow; if (arow > M - 1) arow = M - 1;
  int brow = n0 + srow; if (brow > N - 1) brow = N - 1;
  const unsigned short* agp = Abf + (size_t)arow * K + cbase * 8;
  const float* bgp = W + (size_t)brow * K + cbase * 8;

  f32x4 acc[4][4] = {};
  short8 ra[4];
  float4 rb[8];
#pragma unroll
  for (int c = 0; c < 4; ++c) ra[c] = *(const short8*)(agp + c * 8);
#pragma unroll
  for (int c = 0; c < 4; ++c) {
    rb[2 * c]     = *(const float4*)(bgp + c * 8);
    rb[2 * c + 1] = *(const float4*)(bgp + c * 8 + 4);
  }

  for (int s = 0; s < NS; ++s) {
    __syncthreads();   // prev-step LDS reads done
#pragma unroll
    for (int c = 0; c < 4; ++c) {
      const int slot = (cbase + c) ^ sxor;
      *(short8*)(&As[srow * 64 + slot * 8]) = ra[c];
      u32x4 pk;
      pk.x = (unsigned)f2bf(rb[2 * c].x) | ((unsigned)f2bf(rb[2 * c].y) << 16);
      pk.y = (unsigned)f2bf(rb[2 * c].z) | ((unsigned)f2bf(rb[2 * c].w) << 16);
      pk.z = (unsigned)f2bf(rb[2 * c + 1].x) | ((unsigned)f2bf(rb[2 * c + 1].y) << 16);
      pk.w = (unsigned)f2bf(rb[2 * c + 1].z) | ((unsigned)f2bf(rb[2 * c + 1].w) << 16);
      *(u32x4*)(&Bs[srow * 64 + slot * 8]) = pk;
    }
    __syncthreads();   // staging visible

    short8 ra2[4];
    float4 rb2[8];
    const bool more = (s + 1 < NS);
    if (more) {
      const int k0 = (s + 1) * 64;
#pragma unroll
      for (int c = 0; c < 4; ++c) ra2[c] = *(const short8*)(agp + k0 + c * 8);
#pragma unroll
      for (int c = 0; c < 4; ++c) {
        rb2[2 * c]     = *(const float4*)(bgp + k0 + c * 8);
        rb2[2 * c + 1] = *(const float4*)(bgp + k0 + c * 8 + 4);
      }
    }

#pragma unroll
    for (int ksu = 0; ksu < 2; ++ksu) {
      short8 af[4], bfr[4];
#pragma unroll
      for (int fm = 0; fm < 4; ++fm) {
        const int row = wr * 64 + fm * 16 + llo;
        const int slot = (ksu * 4 + lhi) ^ (row & 7);
        af[fm] = *(const short8*)(&As[row * 64 + slot * 8]);
      }
#pragma unroll
      for (int fn = 0; fn < 4; ++fn) {
        const int row = wc * 64 + fn * 16 + llo;
        const int slot = (ksu * 4 + lhi) ^ (row & 7);
        bfr[fn] = *(const short8*)(&Bs[row * 64 + slot * 8]);
      }
#pragma unroll
      for (int fm = 0; fm < 4; ++fm)
#pragma unroll
        for (int fn = 0; fn < 4; ++fn)
          acc[fm][fn] = __builtin_amdgcn_mfma_f32_16x16x32_bf16(
              af[fm], bfr[fn], acc[fm][fn], 0, 0, 0);
    }

    if (more) {
#pragma unroll
      for (int c = 0; c < 4; ++c) ra[c] = ra2[c];
#pragma unroll
      for (int c = 0; c < 8; ++c) rb[c] = rb2[c];
    }
  }

#pragma unroll
  for (int fn = 0; fn < 4; ++fn) {
    const int gn = n0 + wc * 64 + fn * 16 + llo;
    if (gn >= N) continue;
    const float bv = bias[gn];
#pragma unroll
    for (int fm = 0; fm < 4; ++fm) {
#pragma unroll
      for (int j = 0; j < 4; ++j) {
        const int gm = m0 + wr * 64 + fm * 16 + lhi * 4 + j;
        if (gm >= M) continue;
        size_t ci = REMAP ? ((size_t)((gm & 63) * T_ + (gm >> 6)) * N + gn)
                          : ((size_t)gm * N + gn);
        C[ci] = acc[fm][fn][j] + bv;
      }
    }
  }
}

// ---------------------------------------------------------------------------
// Fused fm GEMM (fc|hh|cc), bf16 MFMA, 64x64 tile, BK=64, 8-way K-split with
// fp32 atomicAdd epilogue (outputs pre-zeroed; bias added by kz==0).
// grid = (44 n-tiles, 8 k-splits). 4 waves 2x2 of 32x32.
// ---------------------------------------------------------------------------
__global__ __launch_bounds__(256)
void fm_gemm_bf16(const unsigned short* __restrict__ fmbf,
                  const float* __restrict__ fcw, const float* __restrict__ hhw,
                  const float* __restrict__ ccw,
                  const float* __restrict__ fcb, const float* __restrict__ hhb,
                  const float* __restrict__ ccb,
                  float* __restrict__ fi, float* __restrict__ hid,
                  float* __restrict__ cel)
{
  __shared__ unsigned short As[64 * 64];   // 8 KB
  __shared__ unsigned short Bs[64 * 64];   // 8 KB
  const int nt = (int)blockIdx.x, kz = (int)blockIdx.y;
  const float* Wp; const float* bp; float* Cp; int ncols, ncol0;
  if (nt < 12)      { Wp = fcw; bp = fcb; Cp = fi;  ncols = 768;  ncol0 = nt * 64; }
  else if (nt < 28) { Wp = hhw; bp = hhb; Cp = hid; ncols = 1024; ncol0 = (nt - 12) * 64; }
  else              { Wp = ccw; bp = ccb; Cp = cel; ncols = 1024; ncol0 = (nt - 28) * 64; }

  const int tid = (int)threadIdx.x;
  const int lane = tid & 63;
  const int w = tid >> 6;
  const int wr = w >> 1, wc = w & 1;
  const int lhi = lane >> 4, llo = lane & 15;
  const int srow = tid >> 2;        // 0..63
  const int cb = (tid & 3) * 2;     // 2 chunks of 8 per thread
  const int sxor = srow & 7;
  const int kbase = kz * 4096;      // 64 steps of 64

  const unsigned short* agp = fmbf + (size_t)srow * FEAT_ + kbase + cb * 8;
  const float* bgp = Wp + (size_t)(ncol0 + srow) * FEAT_ + kbase + cb * 8;

  f32x4 acc[2][2] = {};
  short8 ra[2];
  float4 rb[4];
#pragma unroll
  for (int c = 0; c < 2; ++c) ra[c] = *(const short8*)(agp + c * 8);
#pragma unroll
  for (int c = 0; c < 2; ++c) {
    rb[2 * c]     = *(const float4*)(bgp + c * 8);
    rb[2 * c + 1] = *(const float4*)(bgp + c * 8 + 4);
  }

  for (int s = 0; s < 64; ++s) {
    __syncthreads();
#pragma unroll
    for (int c = 0; c < 2; ++c) {
      const int slot = (cb + c) ^ sxor;
      *(short8*)(&As[srow * 64 + slot * 8]) = ra[c];
      u32x4 pk;
      pk.x = (unsigned)f2bf(rb[2 * c].x) | ((unsigned)f2bf(rb[2 * c].y) << 16);
      pk.y = (unsigned)f2bf(rb[2 * c].z) | ((unsigned)f2bf(rb[2 * c].w) << 16);
      pk.z = (unsigned)f2bf(rb[2 * c + 1].x) | ((unsigned)f2bf(rb[2 * c + 1].y) << 16);
      pk.w = (unsigned)f2bf(rb[2 * c + 1].z) | ((unsigned)f2bf(rb[2 * c + 1].w) << 16);
      *(u32x4*)(&Bs[srow * 64 + slot * 8]) = pk;
    }
    __syncthreads();

    short8 ra2[2];
    float4 rb2[4];
    const bool more = (s + 1 < 64);
    if (more) {
      const int k0 = (s + 1) * 64;
#pragma unroll
      for (int c = 0; c < 2; ++c) ra2[c] = *(const short8*)(agp + k0 + c * 8);
#pragma unroll
      for (int c = 0; c < 2; ++c) {
        rb2[2 * c]     = *(const float4*)(bgp + k0 + c * 8);
        rb2[2 * c + 1] = *(const float4*)(bgp + k0 + c * 8 + 4);
      }
    }

#pragma unroll
    for (int ksu = 0; ksu < 2; ++ksu) {
      short8 af[2], bfr[2];
#pragma unroll
      for (int fm = 0; fm < 2; ++fm) {
        const int row = wr * 32 + fm * 16 + llo;
        const int slot = (ksu * 4 + lhi) ^ (row & 7);
        af[fm] = *(const short8*)(&As[row * 64 + slot * 8]);
      }
#pragma unroll
      for (int fn = 0; fn < 2; ++fn) {
        const int row = wc * 32 + fn * 16 + llo;
        const int slot = (ksu * 4 + lhi) ^ (row & 7);
        bfr[fn] = *(const short8*)(&Bs[row * 64 + slot * 8]);
      }
#pragma unroll
      for (int fm = 0; fm < 2; ++fm)
#pragma unroll
        for (int fn = 0; fn < 2; ++fn)
          acc[fm][fn] = __builtin_amdgcn_mfma_f32_16x16x32_bf16(
              af[fm], bfr[fn], acc[fm][fn], 0, 0, 0);
    }

    if (more) {
#pragma unroll
      for (int c = 0; c < 2; ++c) ra[c] = ra2[c];
#pragma unroll
      for (int c = 0; c < 4; ++c) rb[c] = rb2[c];
    }
  }

#pragma unroll
  for (int fn = 0; fn < 2; ++fn) {
    const int gn = ncol0 + wc * 32 + fn * 16 + llo;
    const float bv = (kz == 0) ? bp[gn] : 0.f;
#pragma unroll
    for (int fm = 0; fm < 2; ++fm) {
#pragma unroll
      for (int j = 0; j < 4; ++j) {
        const int gm = wr * 32 + fm * 16 + lhi * 4 + j;
        atomicAdd(&Cp[(size_t)gm * ncols + gn], acc[fm][fn][j] + bv);
      }
    }
  }
}

// ---------------------------------------------------------------------------
// Fused LSTM step (fp32 exact): block dq owns d in [dq*4, dq*4+4) for all 64
// batches. GEMM h[64,1024] x w_hh_rows[16,1024]^T, add XG slice, pointwise,
// write c (in place, owned) and h -> hs[t].
// ---------------------------------------------------------------------------
__global__ __launch_bounds__(256)
void lstm_step(const float* __restrict__ hin, const float* __restrict__ whh,
               const float* __restrict__ xg, float* __restrict__ cst,
               float* __restrict__ hout)
{
  __shared__ float Asl[64][64];   // [kk][m]
  __shared__ float Bsl[64][16];   // [kk][n]
  __shared__ float gbuf[64][16];
  const int tid = (int)threadIdx.x;
  const int dq = (int)blockIdx.x;          // 0..255
  // staging coords
  const int am = tid >> 2;                  // 0..63 (m row)
  const int akg = tid & 3;                  // k-group (16 kk each)
  const int bn = tid >> 4;                  // 0..15 (gate col)
  const int bkg = tid & 15;                 // kk group of 4
  const int bcol = (dq * 4 + (bn & 3)) + (bn >> 2) * 1024;
  const float* ag = hin + (size_t)am * DM;
  const float* bg = whh + (size_t)bcol * DM;
  // compute coords
  const int tc = tid & 15, tr = tid >> 4;   // n, m-quad
  float acc0 = 0.f, acc1 = 0.f, acc2 = 0.f, acc3 = 0.f;

  float4 pa[4], pb;
#pragma unroll
  for (int i = 0; i < 4; ++i) pa[i] = *(const float4*)(ag + akg * 16 + i * 4);
  pb = *(const float4*)(bg + bkg * 4);

  for (int s = 0; s < 16; ++s) {
    __syncthreads();
#pragma unroll
    for (int i = 0; i < 4; ++i) {
      Asl[akg * 16 + i * 4 + 0][am] = pa[i].x;
      Asl[akg * 16 + i * 4 + 1][am] = pa[i].y;
      Asl[akg * 16 + i * 4 + 2][am] = pa[i].z;
      Asl[akg * 16 + i * 4 + 3][am] = pa[i].w;
    }
    Bsl[bkg * 4 + 0][bn] = pb.x;
    Bsl[bkg * 4 + 1][bn] = pb.y;
    Bsl[bkg * 4 + 2][bn] = pb.z;
    Bsl[bkg * 4 + 3][bn] = pb.w;
    __syncthreads();

    float4 pa2[4]; float4 pb2;
    const bool more = (s + 1 < 16);
    if (more) {
      const int k0 = (s + 1) * 64;
#pragma unroll
      for (int i = 0; i < 4; ++i)
        pa2[i] = *(const float4*)(ag + k0 + akg * 16 + i * 4);
      pb2 = *(const float4*)(bg + k0 + bkg * 4);
    }

#pragma unroll
    for (int kk = 0; kk < 64; ++kk) {
      const float4 a = *(const float4*)(&Asl[kk][tr * 4]);
      const float bv = Bsl[kk][tc];
      acc0 = fmaf(a.x, bv, acc0);
      acc1 = fmaf(a.y, bv, acc1);
      acc2 = fmaf(a.z, bv, acc2);
      acc3 = fmaf(a.w, bv, acc3);
    }

    if (more) {
#pragma unroll
      for (int i = 0; i < 4; ++i) pa[i] = pa2[i];
      pb = pb2;
    }
  }

  __syncthreads();
  gbuf[tr * 4 + 0][tc] = acc0;
  gbuf[tr * 4 + 1][tc] = acc1;
  gbuf[tr * 4 + 2][tc] = acc2;
  gbuf[tr * 4 + 3][tc] = acc3;
  __syncthreads();

  const int m = tid >> 2, dl = tid & 3;
  const int d = dq * 4 + dl;
  const size_t xrow = (size_t)m * (4 * DM);
  float gi = gbuf[m][0 + dl]  + xg[xrow + d];
  float gf = gbuf[m][4 + dl]  + xg[xrow + DM + d];
  float gg = gbuf[m][8 + dl]  + xg[xrow + 2 * DM + d];
  float go = gbuf[m][12 + dl] + xg[xrow + 3 * DM + d];
  float si = 1.f / (1.f + expf(-gi));
  float sf = 1.f / (1.f + expf(-gf));
  float so = 1.f / (1.f + expf(-go));
  float tg = tanhf(gg);
  const size_t ci = (size_t)m * DM + d;
  float c2 = sf * cst[ci] + si * tg;
  float h2 = so * tanhf(c2);
  cst[ci] = c2;
  hout[ci] = h2;
}

// f32 -> bf16 (RNE), 4 elems/thread
__global__ __launch_bounds__(256)
void cvt_f32_bf16(const float* __restrict__ in, unsigned short* __restrict__ op, int n4)
{
  int i = blockIdx.x * 256 + threadIdx.x;
  if (i >= n4) return;
  float4 v = ((const float4*)in)[i];
  unsigned p0 = (unsigned)f2bf(v.x) | ((unsigned)f2bf(v.y) << 16);
  unsigned p1 = (unsigned)f2bf(v.z) | ((unsigned)f2bf(v.w) << 16);
  ((uint2*)op)[i] = make_uint2(p0, p1);
}

// ---------------------------------------------------------------------------
__global__ void addvec(const float* __restrict__ a, const float* __restrict__ b,
                       float* __restrict__ o, int n)
{
  int i = blockIdx.x * blockDim.x + threadIdx.x;
  if (i < n) o[i] = a[i] + b[i];
}

__global__ __launch_bounds__(256)
void gather_attr(const int* __restrict__ attrs, const float* __restrict__ wte,
                 float* __restrict__ attr, float* __restrict__ sattr)
{
  const int ba = blockIdx.x;
  const int idx = attrs[ba];
  const float* src = wte + (size_t)idx * DG;
  for (int e = threadIdx.x; e < DG; e += 256) {
    float v = src[e];
    attr[(size_t)ba * DG + e] = v;
    sattr[(size_t)ba * DG + e] = 1.f / (1.f + expf(-v));
  }
}

__global__ __launch_bounds__(256)
void build_input_emb(const float* __restrict__ fi, const int* __restrict__ cap,
                     const float* __restrict__ wte, float* __restrict__ emb)
{
  const int r = blockIdx.x;
  const int t = r >> 6, b = r & 63;
  const float* src = (t == 0) ? (fi + (size_t)b * DG)
                              : (wte + (size_t)cap[b * T_ + (t - 1)] * DG);
  for (int e = threadIdx.x; e < DG; e += 256)
    emb[(size_t)r * DG + e] = src[e];
}

__global__ __launch_bounds__(256)
void attention_kernel(const float* __restrict__ q, const float* __restrict__ av,
                      float* __restrict__ ctx)
{
  const int r = blockIdx.x;
  const int b = r & 63;
  const int tid = (int)threadIdx.x;
  const float* qr = q + (size_t)r * DG;
  const float* ab = av + (size_t)b * A_ * DG;
  float p0 = 0, p1 = 0, p2 = 0, p3 = 0, p4 = 0;
  for (int e = tid; e < DG; e += 256) {
    float qv = qr[e];
    p0 += qv * ab[0 * DG + e];
    p1 += qv * ab[1 * DG + e];
    p2 += qv * ab[2 * DG + e];
    p3 += qv * ab[3 * DG + e];
    p4 += qv * ab[4 * DG + e];
  }
#pragma unroll
  for (int off = 32; off > 0; off >>= 1) {
    p0 += __shfl_down(p0, off, 64);
    p1 += __shfl_down(p1, off, 64);
    p2 += __shfl_down(p2, off, 64);
    p3 += __shfl_down(p3, off, 64);
    p4 += __shfl_down(p4, off, 64);
  }
  __shared__ float sred[4][5];
  __shared__ float wts[5];
  const int lane = tid & 63, wv = tid >> 6;
  if (lane == 0) {
    sred[wv][0] = p0; sred[wv][1] = p1; sred[wv][2] = p2;
    sred[wv][3] = p3; sred[wv][4] = p4;
  }
  __syncthreads();
  if (tid == 0) {
    float s[5];
#pragma unroll
    for (int a = 0; a < 5; ++a)
      s[a] = sred[0][a] + sred[1][a] + sred[2][a] + sred[3][a];
    float mx = s[0];
#pragma unroll
    for (int a = 1; a < 5; ++a) mx = fmaxf(mx, s[a]);
    float sum = 0.f;
#pragma unroll
    for (int a = 0; a < 5; ++a) { float e_ = expf(s[a] - mx); wts[a] = e_; sum += e_; }
    float inv = 1.f / sum;
#pragma unroll
    for (int a = 0; a < 5; ++a) wts[a] *= inv;
  }
  __syncthreads();
  const float w0 = wts[0], w1 = wts[1], w2 = wts[2], w3 = wts[3], w4 = wts[4];
  for (int e = tid; e < DG; e += 256) {
    float v = w0 * ab[0 * DG + e] + w1 * ab[1 * DG + e] + w2 * ab[2 * DG + e] +
              w3 * ab[3 * DG + e] + w4 * ab[4 * DG + e];
    ctx[(size_t)r * DG + e] = v;
  }
}

// ---------------------------------------------------------------------------
extern "C" void kernel_launch(void* const* d_in, const int* in_sizes, int n_in,
                              void* d_out, int out_size, void* d_ws, size_t ws_size,
                              hipStream_t stream)
{
  (void)in_sizes; (void)n_in; (void)out_size; (void)ws_size;

  const int*   caption    = (const int*)  d_in[0];
  const float* fm         = (const float*)d_in[1];
  const int*   attrs      = (const int*)  d_in[2];
  const float* wte        = (const float*)d_in[3];
  const float* fc_w       = (const float*)d_in[4];
  const float* fc_b       = (const float*)d_in[5];
  const float* hh_w       = (const float*)d_in[6];
  const float* hh_b       = (const float*)d_in[7];
  const float* cc_w       = (const float*)d_in[8];
  const float* cc_b       = (const float*)d_in[9];
  const float* lm_w       = (const float*)d_in[10];
  const float* lm_b       = (const float*)d_in[11];
  const float* iaw_w      = (const float*)d_in[12];
  const float* iaw_b      = (const float*)d_in[13];
  const float* iau_w      = (const float*)d_in[14];
  const float* iau_b      = (const float*)d_in[15];
  const float* indiag_w   = (const float*)d_in[16];
  const float* indiag_b   = (const float*)d_in[17];
  const float* indomain_w = (const float*)d_in[18];
  const float* indomain_b = (const float*)d_in[19];
  const float* oav_w      = (const float*)d_in[20];
  const float* oav_b      = (const float*)d_in[21];
  const float* outdiag_w  = (const float*)d_in[22];
  const float* outdiag_b  = (const float*)d_in[23];
  const float* outdomain_w= (const float*)d_in[24];
  const float* outdomain_b= (const float*)d_in[25];
  const float* w_ih       = (const float*)d_in[26];
  const float* b_ih       = (const float*)d_in[27];
  const float* w_hh       = (const float*)d_in[28];
  const float* b_hh       = (const float*)d_in[29];

  float* out = (float*)d_out;
  float* ws  = (float*)d_ws;

  size_t o = 0;
  float* first_inputs = ws + o; o += (size_t)B_ * DG;       // zeroed (atomic)
  float* hidden       = ws + o; o += (size_t)B_ * DM;       // zeroed (atomic)
  float* cell         = ws + o; o += (size_t)B_ * DM;       // zeroed (atomic)
  float* mi_init      = ws + o; o += (size_t)B_ * DM;
  float* attr         = ws + o; o += (size_t)B_ * A_ * DG;
  float* sattr        = ws + o; o += (size_t)B_ * A_ * DG;
  float* iemb         = ws + o; o += (size_t)1280 * DG;
  float* m1           = ws + o; o += (size_t)1280 * DG;
  float* ctx          = ws + o; o += (size_t)1280 * DG;
  float* t768         = ws + o; o += (size_t)1280 * DG;
  float* minp         = ws + o; o += (size_t)1280 * DM;
  float* XG           = ws + o; o += (size_t)1280 * 4 * DM;
  float* hs           = ws + o; o += (size_t)1280 * DM;
  float* bias2        = ws + o; o += (size_t)4 * DM;
  float* fmbf_f       = ws + o; o += (size_t)B_ * FEAT_ / 2; // 64x32768 bf16
  // buffer reuse (lifetimes verified):
  float* m1o   = m1;    // m1 dead after input attention
  float* ctxo  = ctx;   // ctx dead after t768 GEMM
  float* t1024 = minp;  // model_inputs dead after XG GEMM (+cvt)
  float* outb  = XG;    // XG dead after LSTM loop
  unsigned short* fmbf   = (unsigned short*)fmbf_f;
  unsigned short* minpbf = (unsigned short*)iemb;  // iemb dead after t768 GEMM
  unsigned short* Abf    = (unsigned short*)t768;  // t768 dead after minp GEMM

  const dim3 blk(256);

  hipMemsetAsync(d_ws, 0, (size_t)(B_ * DG + 2 * B_ * DM) * sizeof(float), stream);

  addvec<<<dim3(16), blk, 0, stream>>>(b_ih, b_hh, bias2, 4 * DM);

  // fm -> bf16, then fused fc|hh|cc GEMM (bf16 MFMA, 8-way K-split, atomics)
  cvt_f32_bf16<<<dim3((B_ * FEAT_ / 4) / 256), blk, 0, stream>>>(
      fm, fmbf, B_ * FEAT_ / 4);
  fm_gemm_bf16<<<dim3(44, 8), blk, 0, stream>>>(
      fmbf, fc_w, hh_w, cc_w, fc_b, hh_b, cc_b, first_inputs, hidden, cell);

  gather_attr<<<dim3(B_ * A_), blk, 0, stream>>>(attrs, wte, attr, sattr);
  build_input_emb<<<dim3(1280), blk, 0, stream>>>(first_inputs, caption, wte, iemb);

  gemm_f32<64,16,16,4,1,false><<<dim3(DM / 16, 1), blk, 0, stream>>>(
      first_inputs, iaw_w, iaw_b, nullptr, mi_init, B_, DM, DG);

  gemm_f32<64,64,16,4,4,false><<<dim3(DG / 64, 20), blk, 0, stream>>>(
      iemb, iau_w, iau_b, nullptr, m1, 1280, DG, DG);
  attention_kernel<<<dim3(1280), blk, 0, stream>>>(m1, attr, ctx);
  gemm_f32<64,64,16,4,4,true><<<dim3(DG / 64, 20), blk, 0, stream>>>(
      ctx, indiag_w, indiag_b, iemb, t768, 1280, DG, DG);
  gemm_f32<64,64,16,4,4,false><<<dim3(DM / 64, 20), blk, 0, stream>>>(
      t768, indomain_w, indomain_b, nullptr, minp, 1280, DM, DG);

  // XG rows 0..63 (from mi_init, fp32); rows 64..1279 via bf16 MFMA
  gemm_f32<64,16,16,4,1,false><<<dim3(4 * DM / 16, 1), blk, 0, stream>>>(
      mi_init, w_ih, bias2, nullptr, XG, B_, 4 * DM, DM);
  cvt_f32_bf16<<<dim3((1216 * DM / 4 + 255) / 256), blk, 0, stream>>>(
      minp + (size_t)64 * DM, minpbf, 1216 * DM / 4);
  {
    const int MT = 10, NT = 32, npairs = MT * NT;   // 320
    const int chunk = (npairs + 7) / 8;             // 40
    mfma_gemm_bf16<false><<<dim3(chunk * 8), blk, 0, stream>>>(
        minpbf, w_ih, bias2, XG + (size_t)64 * 4 * DM,
        1216, 4 * DM, DM, MT, chunk, npairs);
  }

  // LSTM: 20 fused steps; hs is the natural h ping-pong
  for (int t = 0; t < T_; ++t) {
    const float* hin = (t == 0) ? hidden : hs + (size_t)(t - 1) * B_ * DM;
    lstm_step<<<dim3(256), blk, 0, stream>>>(
        hin, w_hh, XG + (size_t)t * B_ * 4 * DM, cell, hs + (size_t)t * B_ * DM);
  }

  gemm_f32<64,64,16,4,4,false><<<dim3(DG / 64, 20), blk, 0, stream>>>(
      hs, oav_w, oav_b, nullptr, m1o, 1280, DG, DM);
  attention_kernel<<<dim3(1280), blk, 0, stream>>>(m1o, sattr, ctxo);
  gemm_f32<64,64,16,4,4,true><<<dim3(DM / 64, 20), blk, 0, stream>>>(
      ctxo, outdiag_w, outdiag_b, hs, t1024, 1280, DM, DG);
  gemm_f32<64,64,16,4,4,false><<<dim3(DM / 64, 20), blk, 0, stream>>>(
      t1024, outdomain_w, outdomain_b, nullptr, outb, 1280, DM, DM);

  // lm head: A -> bf16, then XCD-chunked pipelined MFMA GEMM
  cvt_f32_bf16<<<dim3((1280 * DM / 4 + 255) / 256), blk, 0, stream>>>(
      outb, Abf, 1280 * DM / 4);
  {
    const int MT = 10, NT = (VOC + 127) / 128;      // 393
    const int npairs = MT * NT;                     // 3930
    const int chunk = (npairs + 7) / 8;             // 492
    mfma_gemm_bf16<true><<<dim3(chunk * 8), blk, 0, stream>>>(
        Abf, lm_w, lm_b, out, 1280, VOC, DM, MT, chunk, npairs);
  }
}

// Round 4
// 1420.461 us; speedup vs baseline: 4.6465x; 1.5516x over previous
//
#include <hip/hip_runtime.h>
#include <cstdint>
#include <cstddef>

#define B_ 64
#define T_ 20
#define A_ 5
#define DG 768
#define DM 1024
#define VOC 50260
#define FEAT_ 32768

typedef __attribute__((ext_vector_type(8))) short short8;
typedef __attribute__((ext_vector_type(4))) float f32x4;
typedef __attribute__((ext_vector_type(4))) unsigned int u32x4;

__device__ __forceinline__ unsigned short f2bf(float x) {
  unsigned u = __builtin_bit_cast(unsigned, x);
  unsigned r = u + 0x7FFFu + ((u >> 16) & 1u);
  return (unsigned short)(r >> 16);
}

#define GLOAD16(gp, lp)                                                        \
  __builtin_amdgcn_global_load_lds(                                            \
      (const __attribute__((address_space(1))) void*)(gp),                     \
      (__attribute__((address_space(3))) void*)(lp), 16, 0, 0)

// ---------------------------------------------------------------------------
// Generic fp32 GEMM (fallback / tiny layers)
// ---------------------------------------------------------------------------
template<int BM, int BN, int BK, int TM, int TN, bool ADD>
__global__ __launch_bounds__(256)
void gemm_f32(const float* __restrict__ A, const float* __restrict__ W,
              const float* __restrict__ bias, const float* __restrict__ ADDm,
              float* __restrict__ C, int M, int N, int K)
{
  static_assert((BM / TM) * (BN / TN) == 256, "need 256 threads");
  __shared__ float As[BK][BM + 4];
  __shared__ float Ws[BK][BN + 4];
  const int tid = (int)threadIdx.x;
  constexpr int NCG = BN / TN;
  const int tc = tid % NCG;
  const int tr = tid / NCG;
  const int m0 = (int)blockIdx.y * BM;
  const int n0 = (int)blockIdx.x * BN;

  float acc[TM][TN];
#pragma unroll
  for (int i = 0; i < TM; ++i)
#pragma unroll
    for (int j = 0; j < TN; ++j) acc[i][j] = 0.f;

  for (int k0 = 0; k0 < K; k0 += BK) {
#pragma unroll
    for (int i = tid; i < BM * BK; i += 256) {
      int mm = i / BK, kk = i % BK;
      int gm = m0 + mm;
      As[kk][mm] = (gm < M) ? A[(size_t)gm * K + k0 + kk] : 0.f;
    }
#pragma unroll
    for (int i = tid; i < BN * BK; i += 256) {
      int nn = i / BK, kk = i % BK;
      int gn = n0 + nn;
      Ws[kk][nn] = (gn < N) ? W[(size_t)gn * K + k0 + kk] : 0.f;
    }
    __syncthreads();
#pragma unroll
    for (int kk = 0; kk < BK; ++kk) {
      float a[TM], bq[TN];
#pragma unroll
      for (int i = 0; i < TM; ++i) a[i] = As[kk][tr * TM + i];
#pragma unroll
      for (int j = 0; j < TN; ++j) bq[j] = Ws[kk][tc * TN + j];
#pragma unroll
      for (int i = 0; i < TM; ++i)
#pragma unroll
        for (int j = 0; j < TN; ++j)
          acc[i][j] = fmaf(a[i], bq[j], acc[i][j]);
    }
    __syncthreads();
  }

#pragma unroll
  for (int i = 0; i < TM; ++i) {
    const int gm = m0 + tr * TM + i;
    if (gm >= M) continue;
#pragma unroll
    for (int j = 0; j < TN; ++j) {
      const int gn = n0 + tc * TN + j;
      if (gn >= N) continue;
      float v = acc[i][j];
      if (bias != nullptr) v += bias[gn];
      if (ADD) v += ADDm[(size_t)gm * N + gn];
      C[(size_t)gm * N + gn] = v;
    }
  }
}

// ---------------------------------------------------------------------------
// bf16 MFMA GEMM, both operands bf16, global_load_lds staging (m97 structure).
// 128x128 tile, BK=64, 4 waves 2x2 of 64x64. XOR-swizzled LDS achieved via
// pre-swizzled GLOBAL source chunk (rule 21): LDS slot s of row r holds global
// chunk s^(r&7); read side uses slot = k ^ (row&7).
// 1D grid, XCD-chunked n-major pair mapping (round-3 proven: FETCH 841->254MB)
// ---------------------------------------------------------------------------
template<bool REMAP>
__global__ __launch_bounds__(256)
void gemm_bf16_g(const unsigned short* __restrict__ Abf,
                 const unsigned short* __restrict__ Wbf,
                 const float* __restrict__ bias,
                 float* __restrict__ C,
                 int M, int N, int K, int MT, int chunk, int npairs)
{
  __shared__ unsigned short As[128 * 64];   // 16 KB
  __shared__ unsigned short Bs[128 * 64];   // 16 KB
  const int wg = (int)blockIdx.x;
  const int pair = (wg & 7) * chunk + (wg >> 3);
  if (pair >= npairs) return;
  const int nt = pair / MT, mt = pair % MT;
  const int m0 = mt * 128, n0 = nt * 128;

  const int tid = (int)threadIdx.x;
  const int lane = tid & 63;
  const int w = tid >> 6;
  const int wr = w >> 1, wc = w & 1;
  const int lhi = lane >> 4, llo = lane & 15;
  const int NS = K >> 6;

  // staging: wave w owns rows [w*32, w*32+32), 4 issues of 8 rows each.
  const int rloc = lane >> 3;            // 0..7 row within 8-row group
  const int cxor = (lane & 7) ^ rloc;    // global chunk to fetch for this slot
  const size_t kb = (size_t)K * 2;       // row bytes
  const char* asrc[4];
  const char* bsrc[4];
#pragma unroll
  for (int i = 0; i < 4; ++i) {
    int ar = m0 + w * 32 + i * 8 + rloc; if (ar > M - 1) ar = M - 1;
    asrc[i] = (const char*)Abf + (size_t)ar * kb + cxor * 16;
    int br = n0 + w * 32 + i * 8 + rloc; if (br > N - 1) br = N - 1;
    bsrc[i] = (const char*)Wbf + (size_t)br * kb + cxor * 16;
  }
  const unsigned ldsb = (unsigned)(w * 32) * 128;  // wave LDS byte base

  f32x4 acc[4][4] = {};

  for (int s = 0; s < NS; ++s) {
    __syncthreads();   // prev-step LDS reads done
#pragma unroll
    for (int i = 0; i < 4; ++i) {
      GLOAD16(asrc[i], (char*)As + ldsb + i * 1024);
      GLOAD16(bsrc[i], (char*)Bs + ldsb + i * 1024);
      asrc[i] += 128; bsrc[i] += 128;
    }
    __syncthreads();   // staging visible (compiler drains vmcnt before barrier)

#pragma unroll
    for (int ksu = 0; ksu < 2; ++ksu) {
      short8 af[4], bfr[4];
#pragma unroll
      for (int fm = 0; fm < 4; ++fm) {
        const int row = wr * 64 + fm * 16 + llo;
        const int slot = (ksu * 4 + lhi) ^ (row & 7);
        af[fm] = *(const short8*)(&As[row * 64 + slot * 8]);
      }
#pragma unroll
      for (int fn = 0; fn < 4; ++fn) {
        const int row = wc * 64 + fn * 16 + llo;
        const int slot = (ksu * 4 + lhi) ^ (row & 7);
        bfr[fn] = *(const short8*)(&Bs[row * 64 + slot * 8]);
      }
#pragma unroll
      for (int fm = 0; fm < 4; ++fm)
#pragma unroll
        for (int fn = 0; fn < 4; ++fn)
          acc[fm][fn] = __builtin_amdgcn_mfma_f32_16x16x32_bf16(
              af[fm], bfr[fn], acc[fm][fn], 0, 0, 0);
    }
  }

#pragma unroll
  for (int fn = 0; fn < 4; ++fn) {
    const int gn = n0 + wc * 64 + fn * 16 + llo;
    if (gn >= N) continue;
    const float bv = bias[gn];
#pragma unroll
    for (int fm = 0; fm < 4; ++fm) {
#pragma unroll
      for (int j = 0; j < 4; ++j) {
        const int gm = m0 + wr * 64 + fm * 16 + lhi * 4 + j;
        if (gm >= M) continue;
        size_t ci = REMAP ? ((size_t)((gm & 63) * T_ + (gm >> 6)) * N + gn)
                          : ((size_t)gm * N + gn);
        C[ci] = acc[fm][fn][j] + bv;
      }
    }
  }
}

// ---------------------------------------------------------------------------
// Mid-size bf16 MFMA GEMM: 64x64 tile, BK=64, 4 waves 2x2 of 32x32,
// global_load_lds staging, f32 out with bias + optional f32 residual ADD.
// ---------------------------------------------------------------------------
template<bool ADD>
__global__ __launch_bounds__(256)
void gemm_mid_bf16(const unsigned short* __restrict__ Abf,
                   const unsigned short* __restrict__ Wbf,
                   const float* __restrict__ bias, const float* __restrict__ ADDm,
                   float* __restrict__ C, int M, int N, int K)
{
  __shared__ unsigned short As[64 * 64];   // 8 KB
  __shared__ unsigned short Bs[64 * 64];   // 8 KB
  const int tid = (int)threadIdx.x;
  const int lane = tid & 63;
  const int w = tid >> 6;
  const int wr = w >> 1, wc = w & 1;
  const int lhi = lane >> 4, llo = lane & 15;
  const int m0 = (int)blockIdx.y * 64;
  const int n0 = (int)blockIdx.x * 64;

  const int rloc = lane >> 3;
  const int cxor = (lane & 7) ^ rloc;
  const size_t kb = (size_t)K * 2;
  const char* asrc[2];
  const char* bsrc[2];
#pragma unroll
  for (int i = 0; i < 2; ++i) {
    int ar = m0 + w * 16 + i * 8 + rloc; if (ar > M - 1) ar = M - 1;
    asrc[i] = (const char*)Abf + (size_t)ar * kb + cxor * 16;
    int br = n0 + w * 16 + i * 8 + rloc; if (br > N - 1) br = N - 1;
    bsrc[i] = (const char*)Wbf + (size_t)br * kb + cxor * 16;
  }
  const unsigned ldsb = (unsigned)(w * 16) * 128;

  f32x4 acc[2][2] = {};
  const int NS = K >> 6;

  for (int s = 0; s < NS; ++s) {
    __syncthreads();
#pragma unroll
    for (int i = 0; i < 2; ++i) {
      GLOAD16(asrc[i], (char*)As + ldsb + i * 1024);
      GLOAD16(bsrc[i], (char*)Bs + ldsb + i * 1024);
      asrc[i] += 128; bsrc[i] += 128;
    }
    __syncthreads();

#pragma unroll
    for (int ksu = 0; ksu < 2; ++ksu) {
      short8 af[2], bfr[2];
#pragma unroll
      for (int fm = 0; fm < 2; ++fm) {
        const int row = wr * 32 + fm * 16 + llo;
        const int slot = (ksu * 4 + lhi) ^ (row & 7);
        af[fm] = *(const short8*)(&As[row * 64 + slot * 8]);
      }
#pragma unroll
      for (int fn = 0; fn < 2; ++fn) {
        const int row = wc * 32 + fn * 16 + llo;
        const int slot = (ksu * 4 + lhi) ^ (row & 7);
        bfr[fn] = *(const short8*)(&Bs[row * 64 + slot * 8]);
      }
#pragma unroll
      for (int fm = 0; fm < 2; ++fm)
#pragma unroll
        for (int fn = 0; fn < 2; ++fn)
          acc[fm][fn] = __builtin_amdgcn_mfma_f32_16x16x32_bf16(
              af[fm], bfr[fn], acc[fm][fn], 0, 0, 0);
    }
  }

#pragma unroll
  for (int fn = 0; fn < 2; ++fn) {
    const int gn = n0 + wc * 32 + fn * 16 + llo;
    if (gn >= N) continue;
    const float bv = bias[gn];
#pragma unroll
    for (int fm = 0; fm < 2; ++fm) {
#pragma unroll
      for (int j = 0; j < 4; ++j) {
        const int gm = m0 + wr * 32 + fm * 16 + lhi * 4 + j;
        if (gm >= M) continue;
        const size_t ci = (size_t)gm * N + gn;
        float v = acc[fm][fn][j] + bv;
        if (ADD) v += ADDm[ci];
        C[ci] = v;
      }
    }
  }
}

// ---------------------------------------------------------------------------
// Round-3 fallback: bf16 MFMA GEMM with inline f32->bf16 W convert
// ---------------------------------------------------------------------------
template<bool REMAP>
__global__ __launch_bounds__(256)
void mfma_gemm_bf16(const unsigned short* __restrict__ Abf,
                    const float* __restrict__ W,
                    const float* __restrict__ bias,
                    float* __restrict__ C,
                    int M, int N, int K, int MT, int chunk, int npairs)
{
  __shared__ unsigned short As[128 * 64];
  __shared__ unsigned short Bs[128 * 64];
  const int wg = (int)blockIdx.x;
  const int pair = (wg & 7) * chunk + (wg >> 3);
  if (pair >= npairs) return;
  const int nt = pair / MT, mt = pair % MT;
  const int m0 = mt * 128, n0 = nt * 128;

  const int tid = (int)threadIdx.x;
  const int lane = tid & 63;
  const int w = tid >> 6;
  const int wr = w >> 1, wc = w & 1;
  const int lhi = lane >> 4, llo = lane & 15;
  const int srow = tid >> 1;
  const int cbase = (tid & 1) * 4;
  const int sxor = srow & 7;
  const int NS = K >> 6;

  int arow = m0 + srow; if (arow > M - 1) arow = M - 1;
  int brow = n0 + srow; if (brow > N - 1) brow = N - 1;
  const unsigned short* agp = Abf + (size_t)arow * K + cbase * 8;
  const float* bgp = W + (size_t)brow * K + cbase * 8;

  f32x4 acc[4][4] = {};
  short8 ra[4];
  float4 rb[8];
#pragma unroll
  for (int c = 0; c < 4; ++c) ra[c] = *(const short8*)(agp + c * 8);
#pragma unroll
  for (int c = 0; c < 4; ++c) {
    rb[2 * c]     = *(const float4*)(bgp + c * 8);
    rb[2 * c + 1] = *(const float4*)(bgp + c * 8 + 4);
  }

  for (int s = 0; s < NS; ++s) {
    __syncthreads();
#pragma unroll
    for (int c = 0; c < 4; ++c) {
      const int slot = (cbase + c) ^ sxor;
      *(short8*)(&As[srow * 64 + slot * 8]) = ra[c];
      u32x4 pk;
      pk.x = (unsigned)f2bf(rb[2 * c].x) | ((unsigned)f2bf(rb[2 * c].y) << 16);
      pk.y = (unsigned)f2bf(rb[2 * c].z) | ((unsigned)f2bf(rb[2 * c].w) << 16);
      pk.z = (unsigned)f2bf(rb[2 * c + 1].x) | ((unsigned)f2bf(rb[2 * c + 1].y) << 16);
      pk.w = (unsigned)f2bf(rb[2 * c + 1].z) | ((unsigned)f2bf(rb[2 * c + 1].w) << 16);
      *(u32x4*)(&Bs[srow * 64 + slot * 8]) = pk;
    }
    __syncthreads();

    short8 ra2[4];
    float4 rb2[8];
    const bool more = (s + 1 < NS);
    if (more) {
      const int k0 = (s + 1) * 64;
#pragma unroll
      for (int c = 0; c < 4; ++c) ra2[c] = *(const short8*)(agp + k0 + c * 8);
#pragma unroll
      for (int c = 0; c < 4; ++c) {
        rb2[2 * c]     = *(const float4*)(bgp + k0 + c * 8);
        rb2[2 * c + 1] = *(const float4*)(bgp + k0 + c * 8 + 4);
      }
    }

#pragma unroll
    for (int ksu = 0; ksu < 2; ++ksu) {
      short8 af[4], bfr[4];
#pragma unroll
      for (int fm = 0; fm < 4; ++fm) {
        const int row = wr * 64 + fm * 16 + llo;
        const int slot = (ksu * 4 + lhi) ^ (row & 7);
        af[fm] = *(const short8*)(&As[row * 64 + slot * 8]);
      }
#pragma unroll
      for (int fn = 0; fn < 4; ++fn) {
        const int row = wc * 64 + fn * 16 + llo;
        const int slot = (ksu * 4 + lhi) ^ (row & 7);
        bfr[fn] = *(const short8*)(&Bs[row * 64 + slot * 8]);
      }
#pragma unroll
      for (int fm = 0; fm < 4; ++fm)
#pragma unroll
        for (int fn = 0; fn < 4; ++fn)
          acc[fm][fn] = __builtin_amdgcn_mfma_f32_16x16x32_bf16(
              af[fm], bfr[fn], acc[fm][fn], 0, 0, 0);
    }

    if (more) {
#pragma unroll
      for (int c = 0; c < 4; ++c) ra[c] = ra2[c];
#pragma unroll
      for (int c = 0; c < 8; ++c) rb[c] = rb2[c];
    }
  }

#pragma unroll
  for (int fn = 0; fn < 4; ++fn) {
    const int gn = n0 + wc * 64 + fn * 16 + llo;
    if (gn >= N) continue;
    const float bv = bias[gn];
#pragma unroll
    for (int fm = 0; fm < 4; ++fm) {
#pragma unroll
      for (int j = 0; j < 4; ++j) {
        const int gm = m0 + wr * 64 + fm * 16 + lhi * 4 + j;
        if (gm >= M) continue;
        size_t ci = REMAP ? ((size_t)((gm & 63) * T_ + (gm >> 6)) * N + gn)
                          : ((size_t)gm * N + gn);
        C[ci] = acc[fm][fn][j] + bv;
      }
    }
  }
}

// ---------------------------------------------------------------------------
// Fused fm GEMM (fc|hh|cc), bf16 MFMA, 8-way K-split, fp32 atomic epilogue.
// ---------------------------------------------------------------------------
__global__ __launch_bounds__(256)
void fm_gemm_bf16(const unsigned short* __restrict__ fmbf,
                  const float* __restrict__ fcw, const float* __restrict__ hhw,
                  const float* __restrict__ ccw,
                  const float* __restrict__ fcb, const float* __restrict__ hhb,
                  const float* __restrict__ ccb,
                  float* __restrict__ fi, float* __restrict__ hid,
                  float* __restrict__ cel)
{
  __shared__ unsigned short As[64 * 64];
  __shared__ unsigned short Bs[64 * 64];
  const int nt = (int)blockIdx.x, kz = (int)blockIdx.y;
  const float* Wp; const float* bp; float* Cp; int ncols, ncol0;
  if (nt < 12)      { Wp = fcw; bp = fcb; Cp = fi;  ncols = 768;  ncol0 = nt * 64; }
  else if (nt < 28) { Wp = hhw; bp = hhb; Cp = hid; ncols = 1024; ncol0 = (nt - 12) * 64; }
  else              { Wp = ccw; bp = ccb; Cp = cel; ncols = 1024; ncol0 = (nt - 28) * 64; }

  const int tid = (int)threadIdx.x;
  const int lane = tid & 63;
  const int w = tid >> 6;
  const int wr = w >> 1, wc = w & 1;
  const int lhi = lane >> 4, llo = lane & 15;
  const int srow = tid >> 2;
  const int cb = (tid & 3) * 2;
  const int sxor = srow & 7;
  const int kbase = kz * 4096;

  const unsigned short* agp = fmbf + (size_t)srow * FEAT_ + kbase + cb * 8;
  const float* bgp = Wp + (size_t)(ncol0 + srow) * FEAT_ + kbase + cb * 8;

  f32x4 acc[2][2] = {};
  short8 ra[2];
  float4 rb[4];
#pragma unroll
  for (int c = 0; c < 2; ++c) ra[c] = *(const short8*)(agp + c * 8);
#pragma unroll
  for (int c = 0; c < 2; ++c) {
    rb[2 * c]     = *(const float4*)(bgp + c * 8);
    rb[2 * c + 1] = *(const float4*)(bgp + c * 8 + 4);
  }

  for (int s = 0; s < 64; ++s) {
    __syncthreads();
#pragma unroll
    for (int c = 0; c < 2; ++c) {
      const int slot = (cb + c) ^ sxor;
      *(short8*)(&As[srow * 64 + slot * 8]) = ra[c];
      u32x4 pk;
      pk.x = (unsigned)f2bf(rb[2 * c].x) | ((unsigned)f2bf(rb[2 * c].y) << 16);
      pk.y = (unsigned)f2bf(rb[2 * c].z) | ((unsigned)f2bf(rb[2 * c].w) << 16);
      pk.z = (unsigned)f2bf(rb[2 * c + 1].x) | ((unsigned)f2bf(rb[2 * c + 1].y) << 16);
      pk.w = (unsigned)f2bf(rb[2 * c + 1].z) | ((unsigned)f2bf(rb[2 * c + 1].w) << 16);
      *(u32x4*)(&Bs[srow * 64 + slot * 8]) = pk;
    }
    __syncthreads();

    short8 ra2[2];
    float4 rb2[4];
    const bool more = (s + 1 < 64);
    if (more) {
      const int k0 = (s + 1) * 64;
#pragma unroll
      for (int c = 0; c < 2; ++c) ra2[c] = *(const short8*)(agp + k0 + c * 8);
#pragma unroll
      for (int c = 0; c < 2; ++c) {
        rb2[2 * c]     = *(const float4*)(bgp + k0 + c * 8);
        rb2[2 * c + 1] = *(const float4*)(bgp + k0 + c * 8 + 4);
      }
    }

#pragma unroll
    for (int ksu = 0; ksu < 2; ++ksu) {
      short8 af[2], bfr[2];
#pragma unroll
      for (int fm = 0; fm < 2; ++fm) {
        const int row = wr * 32 + fm * 16 + llo;
        const int slot = (ksu * 4 + lhi) ^ (row & 7);
        af[fm] = *(const short8*)(&As[row * 64 + slot * 8]);
      }
#pragma unroll
      for (int fn = 0; fn < 2; ++fn) {
        const int row = wc * 32 + fn * 16 + llo;
        const int slot = (ksu * 4 + lhi) ^ (row & 7);
        bfr[fn] = *(const short8*)(&Bs[row * 64 + slot * 8]);
      }
#pragma unroll
      for (int fm = 0; fm < 2; ++fm)
#pragma unroll
        for (int fn = 0; fn < 2; ++fn)
          acc[fm][fn] = __builtin_amdgcn_mfma_f32_16x16x32_bf16(
              af[fm], bfr[fn], acc[fm][fn], 0, 0, 0);
    }

    if (more) {
#pragma unroll
      for (int c = 0; c < 2; ++c) ra[c] = ra2[c];
#pragma unroll
      for (int c = 0; c < 4; ++c) rb[c] = rb2[c];
    }
  }

#pragma unroll
  for (int fn = 0; fn < 2; ++fn) {
    const int gn = ncol0 + wc * 32 + fn * 16 + llo;
    const float bv = (kz == 0) ? bp[gn] : 0.f;
#pragma unroll
    for (int fm = 0; fm < 2; ++fm) {
#pragma unroll
      for (int j = 0; j < 4; ++j) {
        const int gm = wr * 32 + fm * 16 + lhi * 4 + j;
        atomicAdd(&Cp[(size_t)gm * ncols + gn], acc[fm][fn][j] + bv);
      }
    }
  }
}

// ---------------------------------------------------------------------------
// Fused LSTM step (fp32 exact)
// ---------------------------------------------------------------------------
__global__ __launch_bounds__(256)
void lstm_step(const float* __restrict__ hin, const float* __restrict__ whh,
               const float* __restrict__ xg, float* __restrict__ cst,
               float* __restrict__ hout)
{
  __shared__ float Asl[64][64];
  __shared__ float Bsl[64][16];
  __shared__ float gbuf[64][16];
  const int tid = (int)threadIdx.x;
  const int dq = (int)blockIdx.x;
  const int am = tid >> 2;
  const int akg = tid & 3;
  const int bn = tid >> 4;
  const int bkg = tid & 15;
  const int bcol = (dq * 4 + (bn & 3)) + (bn >> 2) * 1024;
  const float* ag = hin + (size_t)am * DM;
  const float* bg = whh + (size_t)bcol * DM;
  const int tc = tid & 15, tr = tid >> 4;
  float acc0 = 0.f, acc1 = 0.f, acc2 = 0.f, acc3 = 0.f;

  float4 pa[4], pb;
#pragma unroll
  for (int i = 0; i < 4; ++i) pa[i] = *(const float4*)(ag + akg * 16 + i * 4);
  pb = *(const float4*)(bg + bkg * 4);

  for (int s = 0; s < 16; ++s) {
    __syncthreads();
#pragma unroll
    for (int i = 0; i < 4; ++i) {
      Asl[akg * 16 + i * 4 + 0][am] = pa[i].x;
      Asl[akg * 16 + i * 4 + 1][am] = pa[i].y;
      Asl[akg * 16 + i * 4 + 2][am] = pa[i].z;
      Asl[akg * 16 + i * 4 + 3][am] = pa[i].w;
    }
    Bsl[bkg * 4 + 0][bn] = pb.x;
    Bsl[bkg * 4 + 1][bn] = pb.y;
    Bsl[bkg * 4 + 2][bn] = pb.z;
    Bsl[bkg * 4 + 3][bn] = pb.w;
    __syncthreads();

    float4 pa2[4]; float4 pb2;
    const bool more = (s + 1 < 16);
    if (more) {
      const int k0 = (s + 1) * 64;
#pragma unroll
      for (int i = 0; i < 4; ++i)
        pa2[i] = *(const float4*)(ag + k0 + akg * 16 + i * 4);
      pb2 = *(const float4*)(bg + k0 + bkg * 4);
    }

#pragma unroll
    for (int kk = 0; kk < 64; ++kk) {
      const float4 a = *(const float4*)(&Asl[kk][tr * 4]);
      const float bv = Bsl[kk][tc];
      acc0 = fmaf(a.x, bv, acc0);
      acc1 = fmaf(a.y, bv, acc1);
      acc2 = fmaf(a.z, bv, acc2);
      acc3 = fmaf(a.w, bv, acc3);
    }

    if (more) {
#pragma unroll
      for (int i = 0; i < 4; ++i) pa[i] = pa2[i];
      pb = pb2;
    }
  }

  __syncthreads();
  gbuf[tr * 4 + 0][tc] = acc0;
  gbuf[tr * 4 + 1][tc] = acc1;
  gbuf[tr * 4 + 2][tc] = acc2;
  gbuf[tr * 4 + 3][tc] = acc3;
  __syncthreads();

  const int m = tid >> 2, dl = tid & 3;
  const int d = dq * 4 + dl;
  const size_t xrow = (size_t)m * (4 * DM);
  float gi = gbuf[m][0 + dl]  + xg[xrow + d];
  float gf = gbuf[m][4 + dl]  + xg[xrow + DM + d];
  float gg = gbuf[m][8 + dl]  + xg[xrow + 2 * DM + d];
  float go = gbuf[m][12 + dl] + xg[xrow + 3 * DM + d];
  float si = 1.f / (1.f + expf(-gi));
  float sf = 1.f / (1.f + expf(-gf));
  float so = 1.f / (1.f + expf(-go));
  float tg = tanhf(gg);
  const size_t ci = (size_t)m * DM + d;
  float c2 = sf * cst[ci] + si * tg;
  float h2 = so * tanhf(c2);
  cst[ci] = c2;
  hout[ci] = h2;
}

// f32 -> bf16 (RNE), 4 elems/thread
__global__ __launch_bounds__(256)
void cvt_f32_bf16(const float* __restrict__ in, unsigned short* __restrict__ op, int n4)
{
  int i = blockIdx.x * 256 + threadIdx.x;
  if (i >= n4) return;
  float4 v = ((const float4*)in)[i];
  unsigned p0 = (unsigned)f2bf(v.x) | ((unsigned)f2bf(v.y) << 16);
  unsigned p1 = (unsigned)f2bf(v.z) | ((unsigned)f2bf(v.w) << 16);
  ((uint2*)op)[i] = make_uint2(p0, p1);
}

// ---------------------------------------------------------------------------
__global__ void addvec(const float* __restrict__ a, const float* __restrict__ b,
                       float* __restrict__ o, int n)
{
  int i = blockIdx.x * blockDim.x + threadIdx.x;
  if (i < n) o[i] = a[i] + b[i];
}

__global__ __launch_bounds__(256)
void gather_attr(const int* __restrict__ attrs, const float* __restrict__ wte,
                 float* __restrict__ attr, float* __restrict__ sattr)
{
  const int ba = blockIdx.x;
  const int idx = attrs[ba];
  const float* src = wte + (size_t)idx * DG;
  for (int e = threadIdx.x; e < DG; e += 256) {
    float v = src[e];
    attr[(size_t)ba * DG + e] = v;
    sattr[(size_t)ba * DG + e] = 1.f / (1.f + expf(-v));
  }
}

__global__ __launch_bounds__(256)
void build_input_emb(const float* __restrict__ fi, const int* __restrict__ cap,
                     const float* __restrict__ wte, float* __restrict__ emb)
{
  const int r = blockIdx.x;
  const int t = r >> 6, b = r & 63;
  const float* src = (t == 0) ? (fi + (size_t)b * DG)
                              : (wte + (size_t)cap[b * T_ + (t - 1)] * DG);
  for (int e = threadIdx.x; e < DG; e += 256)
    emb[(size_t)r * DG + e] = src[e];
}

__global__ __launch_bounds__(256)
void attention_kernel(const float* __restrict__ q, const float* __restrict__ av,
                      float* __restrict__ ctx)
{
  const int r = blockIdx.x;
  const int b = r & 63;
  const int tid = (int)threadIdx.x;
  const float* qr = q + (size_t)r * DG;
  const float* ab = av + (size_t)b * A_ * DG;
  float p0 = 0, p1 = 0, p2 = 0, p3 = 0, p4 = 0;
  for (int e = tid; e < DG; e += 256) {
    float qv = qr[e];
    p0 += qv * ab[0 * DG + e];
    p1 += qv * ab[1 * DG + e];
    p2 += qv * ab[2 * DG + e];
    p3 += qv * ab[3 * DG + e];
    p4 += qv * ab[4 * DG + e];
  }
#pragma unroll
  for (int off = 32; off > 0; off >>= 1) {
    p0 += __shfl_down(p0, off, 64);
    p1 += __shfl_down(p1, off, 64);
    p2 += __shfl_down(p2, off, 64);
    p3 += __shfl_down(p3, off, 64);
    p4 += __shfl_down(p4, off, 64);
  }
  __shared__ float sred[4][5];
  __shared__ float wts[5];
  const int lane = tid & 63, wv = tid >> 6;
  if (lane == 0) {
    sred[wv][0] = p0; sred[wv][1] = p1; sred[wv][2] = p2;
    sred[wv][3] = p3; sred[wv][4] = p4;
  }
  __syncthreads();
  if (tid == 0) {
    float s[5];
#pragma unroll
    for (int a = 0; a < 5; ++a)
      s[a] = sred[0][a] + sred[1][a] + sred[2][a] + sred[3][a];
    float mx = s[0];
#pragma unroll
    for (int a = 1; a < 5; ++a) mx = fmaxf(mx, s[a]);
    float sum = 0.f;
#pragma unroll
    for (int a = 0; a < 5; ++a) { float e_ = expf(s[a] - mx); wts[a] = e_; sum += e_; }
    float inv = 1.f / sum;
#pragma unroll
    for (int a = 0; a < 5; ++a) wts[a] *= inv;
  }
  __syncthreads();
  const float w0 = wts[0], w1 = wts[1], w2 = wts[2], w3 = wts[3], w4 = wts[4];
  for (int e = tid; e < DG; e += 256) {
    float v = w0 * ab[0 * DG + e] + w1 * ab[1 * DG + e] + w2 * ab[2 * DG + e] +
              w3 * ab[3 * DG + e] + w4 * ab[4 * DG + e];
    ctx[(size_t)r * DG + e] = v;
  }
}

// ---------------------------------------------------------------------------
extern "C" void kernel_launch(void* const* d_in, const int* in_sizes, int n_in,
                              void* d_out, int out_size, void* d_ws, size_t ws_size,
                              hipStream_t stream)
{
  (void)in_sizes; (void)n_in; (void)out_size;

  const int*   caption    = (const int*)  d_in[0];
  const float* fm         = (const float*)d_in[1];
  const int*   attrs      = (const int*)  d_in[2];
  const float* wte        = (const float*)d_in[3];
  const float* fc_w       = (const float*)d_in[4];
  const float* fc_b       = (const float*)d_in[5];
  const float* hh_w       = (const float*)d_in[6];
  const float* hh_b       = (const float*)d_in[7];
  const float* cc_w       = (const float*)d_in[8];
  const float* cc_b       = (const float*)d_in[9];
  const float* lm_w       = (const float*)d_in[10];
  const float* lm_b       = (const float*)d_in[11];
  const float* iaw_w      = (const float*)d_in[12];
  const float* iaw_b      = (const float*)d_in[13];
  const float* iau_w      = (const float*)d_in[14];
  const float* iau_b      = (const float*)d_in[15];
  const float* indiag_w   = (const float*)d_in[16];
  const float* indiag_b   = (const float*)d_in[17];
  const float* indomain_w = (const float*)d_in[18];
  const float* indomain_b = (const float*)d_in[19];
  const float* oav_w      = (const float*)d_in[20];
  const float* oav_b      = (const float*)d_in[21];
  const float* outdiag_w  = (const float*)d_in[22];
  const float* outdiag_b  = (const float*)d_in[23];
  const float* outdomain_w= (const float*)d_in[24];
  const float* outdomain_b= (const float*)d_in[25];
  const float* w_ih       = (const float*)d_in[26];
  const float* b_ih       = (const float*)d_in[27];
  const float* w_hh       = (const float*)d_in[28];
  const float* b_hh       = (const float*)d_in[29];

  float* out = (float*)d_out;
  float* ws  = (float*)d_ws;

  // ---- base workspace (floats)
  size_t o = 0;
  float* first_inputs = ws + o; o += (size_t)B_ * DG;       // zeroed (atomic)
  float* hidden       = ws + o; o += (size_t)B_ * DM;       // zeroed (atomic)
  float* cell         = ws + o; o += (size_t)B_ * DM;       // zeroed (atomic)
  float* mi_init      = ws + o; o += (size_t)B_ * DM;
  float* attr         = ws + o; o += (size_t)B_ * A_ * DG;
  float* sattr        = ws + o; o += (size_t)B_ * A_ * DG;
  float* iemb         = ws + o; o += (size_t)1280 * DG;
  float* m1           = ws + o; o += (size_t)1280 * DG;
  float* ctx          = ws + o; o += (size_t)1280 * DG;
  float* t768         = ws + o; o += (size_t)1280 * DG;
  float* minp         = ws + o; o += (size_t)1280 * DM;
  float* XG           = ws + o; o += (size_t)1280 * 4 * DM;
  float* hs           = ws + o; o += (size_t)1280 * DM;
  float* bias2        = ws + o; o += (size_t)4 * DM;
  float* fmbf_f       = ws + o; o += (size_t)B_ * FEAT_ / 2;
  const size_t o_base = o;
  // ---- extended region (bf16-weight path)
  unsigned short* lmwbf = (unsigned short*)(ws + o); o += (size_t)VOC * DM / 2;
  unsigned short* wihbf = (unsigned short*)(ws + o); o += (size_t)4 * DM * DM / 2;
  unsigned short* iaubf = (unsigned short*)(ws + o); o += (size_t)DG * DG / 2;
  unsigned short* indgbf= (unsigned short*)(ws + o); o += (size_t)DG * DG / 2;
  unsigned short* indobf= (unsigned short*)(ws + o); o += (size_t)DM * DG / 2;
  unsigned short* oavbf = (unsigned short*)(ws + o); o += (size_t)DG * DM / 2;
  unsigned short* outdgbf=(unsigned short*)(ws + o); o += (size_t)DM * DG / 2;
  unsigned short* outdobf=(unsigned short*)(ws + o); o += (size_t)DM * DM / 2;
  unsigned short* actbf = (unsigned short*)(ws + o); o += (size_t)1280 * DM / 2;
  const size_t need_ext = o * sizeof(float);
  const bool EXT = (ws_size >= need_ext);

  // fallback aliases (round-3 path)
  float* m1o   = m1;
  float* ctxo  = ctx;
  float* t1024 = minp;
  float* outb  = XG;
  unsigned short* fmbf   = (unsigned short*)fmbf_f;
  unsigned short* minpbf = (unsigned short*)iemb;
  unsigned short* Abf    = (unsigned short*)t768;
  (void)o_base;

  const dim3 blk(256);

  hipMemsetAsync(d_ws, 0, (size_t)(B_ * DG + 2 * B_ * DM) * sizeof(float), stream);
  addvec<<<dim3(16), blk, 0, stream>>>(b_ih, b_hh, bias2, 4 * DM);

  if (EXT) {
    // one-time weight converts
    cvt_f32_bf16<<<dim3((VOC * DM / 4 + 255) / 256), blk, 0, stream>>>(lm_w, lmwbf, VOC * DM / 4);
    cvt_f32_bf16<<<dim3((4 * DM * DM / 4) / 256), blk, 0, stream>>>(w_ih, wihbf, 4 * DM * DM / 4);
    cvt_f32_bf16<<<dim3((DG * DG / 4) / 256), blk, 0, stream>>>(iau_w, iaubf, DG * DG / 4);
    cvt_f32_bf16<<<dim3((DG * DG / 4) / 256), blk, 0, stream>>>(indiag_w, indgbf, DG * DG / 4);
    cvt_f32_bf16<<<dim3((DM * DG / 4) / 256), blk, 0, stream>>>(indomain_w, indobf, DM * DG / 4);
    cvt_f32_bf16<<<dim3((DG * DM / 4) / 256), blk, 0, stream>>>(oav_w, oavbf, DG * DM / 4);
    cvt_f32_bf16<<<dim3((DM * DG / 4) / 256), blk, 0, stream>>>(outdiag_w, outdgbf, DM * DG / 4);
    cvt_f32_bf16<<<dim3((DM * DM / 4) / 256), blk, 0, stream>>>(outdomain_w, outdobf, DM * DM / 4);
  }

  // fm path
  cvt_f32_bf16<<<dim3((B_ * FEAT_ / 4) / 256), blk, 0, stream>>>(fm, fmbf, B_ * FEAT_ / 4);
  fm_gemm_bf16<<<dim3(44, 8), blk, 0, stream>>>(
      fmbf, fc_w, hh_w, cc_w, fc_b, hh_b, cc_b, first_inputs, hidden, cell);

  gather_attr<<<dim3(B_ * A_), blk, 0, stream>>>(attrs, wte, attr, sattr);
  build_input_emb<<<dim3(1280), blk, 0, stream>>>(first_inputs, caption, wte, iemb);

  gemm_f32<64,16,16,4,1,false><<<dim3(DM / 16, 1), blk, 0, stream>>>(
      first_inputs, iaw_w, iaw_b, nullptr, mi_init, B_, DM, DG);

  if (EXT) {
    // input attention chain (bf16 MFMA mids)
    cvt_f32_bf16<<<dim3((1280 * DG / 4) / 256), blk, 0, stream>>>(iemb, actbf, 1280 * DG / 4);
    gemm_mid_bf16<false><<<dim3(DG / 64, 20), blk, 0, stream>>>(
        actbf, iaubf, iau_b, nullptr, m1, 1280, DG, DG);
    attention_kernel<<<dim3(1280), blk, 0, stream>>>(m1, attr, ctx);
    cvt_f32_bf16<<<dim3((1280 * DG / 4) / 256), blk, 0, stream>>>(ctx, actbf, 1280 * DG / 4);
    gemm_mid_bf16<true><<<dim3(DG / 64, 20), blk, 0, stream>>>(
        actbf, indgbf, indiag_b, iemb, t768, 1280, DG, DG);
    cvt_f32_bf16<<<dim3((1280 * DG / 4) / 256), blk, 0, stream>>>(t768, actbf, 1280 * DG / 4);
    gemm_mid_bf16<false><<<dim3(DM / 64, 20), blk, 0, stream>>>(
        actbf, indobf, indomain_b, nullptr, minp, 1280, DM, DG);

    // XG: rows 0..63 (fp32, exact LSTM input), rows 64.. via bf16 g-kernel
    gemm_f32<64,16,16,4,1,false><<<dim3(4 * DM / 16, 1), blk, 0, stream>>>(
        mi_init, w_ih, bias2, nullptr, XG, B_, 4 * DM, DM);
    cvt_f32_bf16<<<dim3((1216 * DM / 4 + 255) / 256), blk, 0, stream>>>(
        minp + (size_t)64 * DM, actbf, 1216 * DM / 4);
    {
      const int MT = 10, NT = 32, npairs = MT * NT, chunk = (npairs + 7) / 8;
      gemm_bf16_g<false><<<dim3(chunk * 8), blk, 0, stream>>>(
          actbf, wihbf, bias2, XG + (size_t)64 * 4 * DM, 1216, 4 * DM, DM,
          MT, chunk, npairs);
    }
  } else {
    gemm_f32<64,64,16,4,4,false><<<dim3(DG / 64, 20), blk, 0, stream>>>(
        iemb, iau_w, iau_b, nullptr, m1, 1280, DG, DG);
    attention_kernel<<<dim3(1280), blk, 0, stream>>>(m1, attr, ctx);
    gemm_f32<64,64,16,4,4,true><<<dim3(DG / 64, 20), blk, 0, stream>>>(
        ctx, indiag_w, indiag_b, iemb, t768, 1280, DG, DG);
    gemm_f32<64,64,16,4,4,false><<<dim3(DM / 64, 20), blk, 0, stream>>>(
        t768, indomain_w, indomain_b, nullptr, minp, 1280, DM, DG);
    gemm_f32<64,16,16,4,1,false><<<dim3(4 * DM / 16, 1), blk, 0, stream>>>(
        mi_init, w_ih, bias2, nullptr, XG, B_, 4 * DM, DM);
    cvt_f32_bf16<<<dim3((1216 * DM / 4 + 255) / 256), blk, 0, stream>>>(
        minp + (size_t)64 * DM, minpbf, 1216 * DM / 4);
    const int MT = 10, NT = 32, npairs = MT * NT, chunk = (npairs + 7) / 8;
    mfma_gemm_bf16<false><<<dim3(chunk * 8), blk, 0, stream>>>(
        minpbf, w_ih, bias2, XG + (size_t)64 * 4 * DM, 1216, 4 * DM, DM,
        MT, chunk, npairs);
  }

  // LSTM: 20 fused steps (fp32)
  for (int t = 0; t < T_; ++t) {
    const float* hin = (t == 0) ? hidden : hs + (size_t)(t - 1) * B_ * DM;
    lstm_step<<<dim3(256), blk, 0, stream>>>(
        hin, w_hh, XG + (size_t)t * B_ * 4 * DM, cell, hs + (size_t)t * B_ * DM);
  }

  if (EXT) {
    // output attention chain (bf16 MFMA mids)
    cvt_f32_bf16<<<dim3((1280 * DM / 4) / 256), blk, 0, stream>>>(hs, actbf, 1280 * DM / 4);
    gemm_mid_bf16<false><<<dim3(DG / 64, 20), blk, 0, stream>>>(
        actbf, oavbf, oav_b, nullptr, m1o, 1280, DG, DM);
    attention_kernel<<<dim3(1280), blk, 0, stream>>>(m1o, sattr, ctxo);
    cvt_f32_bf16<<<dim3((1280 * DG / 4) / 256), blk, 0, stream>>>(ctxo, actbf, 1280 * DG / 4);
    gemm_mid_bf16<true><<<dim3(DM / 64, 20), blk, 0, stream>>>(
        actbf, outdgbf, outdiag_b, hs, t1024, 1280, DM, DG);
    cvt_f32_bf16<<<dim3((1280 * DM / 4) / 256), blk, 0, stream>>>(t1024, actbf, 1280 * DM / 4);
    gemm_mid_bf16<false><<<dim3(DM / 64, 20), blk, 0, stream>>>(
        actbf, outdobf, outdomain_b, nullptr, outb, 1280, DM, DM);

    // lm head: A -> bf16, bf16-W g-kernel
    cvt_f32_bf16<<<dim3((1280 * DM / 4) / 256), blk, 0, stream>>>(outb, actbf, 1280 * DM / 4);
    const int MT = 10, NT = (VOC + 127) / 128, npairs = MT * NT;
    const int chunk = (npairs + 7) / 8;
    gemm_bf16_g<true><<<dim3(chunk * 8), blk, 0, stream>>>(
        actbf, lmwbf, lm_b, out, 1280, VOC, DM, MT, chunk, npairs);
  } else {
    gemm_f32<64,64,16,4,4,false><<<dim3(DG / 64, 20), blk, 0, stream>>>(
        hs, oav_w, oav_b, nullptr, m1o, 1280, DG, DM);
    attention_kernel<<<dim3(1280), blk, 0, stream>>>(m1o, sattr, ctxo);
    gemm_f32<64,64,16,4,4,true><<<dim3(DM / 64, 20), blk, 0, stream>>>(
        ctxo, outdiag_w, outdiag_b, hs, t1024, 1280, DM, DG);
    gemm_f32<64,64,16,4,4,false><<<dim3(DM / 64, 20), blk, 0, stream>>>(
        t1024, outdomain_w, outdomain_b, nullptr, outb, 1280, DM, DM);
    cvt_f32_bf16<<<dim3((1280 * DM / 4 + 255) / 256), blk, 0, stream>>>(
        outb, Abf, 1280 * DM / 4);
    const int MT = 10, NT = (VOC + 127) / 128, npairs = MT * NT;
    const int chunk = (npairs + 7) / 8;
    mfma_gemm_bf16<true><<<dim3(chunk * 8), blk, 0, stream>>>(
        Abf, lm_w, lm_b, out, 1280, VOC, DM, MT, chunk, npairs);
  }
}